// Round 2
// baseline (3439.484 us; speedup 1.0000x reference)
//
#include <hip/hip_runtime.h>
#include <math.h>

// AutoregressiveTransformer on MI355X (gfx950).
// Round 2: same bf16-MFMA structure as round 1, workspace shrunk 349->115 MB
// (per-layer weight staging, per-batch attention) + forced 16B LDS alignment.

typedef unsigned short bfu;                                  // raw bf16 bits
typedef short  s16x8 __attribute__((ext_vector_type(8)));    // 8 bf16 = 4 VGPR (MFMA A/B frag)
typedef float  f32x4 __attribute__((ext_vector_type(4)));    // MFMA C/D frag

__device__ __forceinline__ bfu f2b(float f) {                // fp32 -> bf16 (RNE)
  unsigned int u = __float_as_uint(f);
  unsigned int r = (u + 0x7fffu + ((u >> 16) & 1u)) >> 16;
  return (bfu)r;
}
__device__ __forceinline__ float b2f(bfu h) {
  return __uint_as_float(((unsigned int)h) << 16);
}

// ---------------------------------------------------------------------------
// Generic GEMM: C[m,n] = sum_k A[m,k] * Bt[n,k]  (both operands K-contiguous)
// bf16 in, fp32 accumulate. Tile TM x TN, BK=32, 16x16x32 MFMA, 4x4 frags per
// wave (wave owns 64x64). Optional batched (grid.z) with outer/inner strides.
// Epilogue: optional scale+causal mask, bias, relu; fp32 or bf16 output.
// ---------------------------------------------------------------------------
template<int TM, int TN, bool OUT_BF16, bool RELU, bool CAUSAL, bool HAS_BIAS>
__global__ __launch_bounds__((TM/64)*(TN/64)*64)
void gemm_bt(const bfu* __restrict__ A, long lda, long sAo, long sAi,
             const bfu* __restrict__ B, long ldb, long sBo, long sBi,
             void* __restrict__ Cv, long ldc, long sCo, long sCi,
             const float* __restrict__ bias,
             int K, int zInner, float scale)
{
  constexpr int BK  = 32;
  constexpr int WX  = TN / 64, WY = TM / 64;
  constexpr int NT  = WX * WY * 64;
  constexpr int AIT = (TM * BK) / (NT * 8);
  constexpr int BIT = (TN * BK) / (NT * 8);

  __shared__ __align__(16) bfu As[TM * BK];
  __shared__ __align__(16) bfu Bs[TN * BK];

  const int t  = threadIdx.x;
  const int z  = blockIdx.z;
  const int zo = z / zInner, zi = z - zo * zInner;
  A += (long)zo * sAo + (long)zi * sAi;
  B += (long)zo * sBo + (long)zi * sBi;
  const long cBase = (long)zo * sCo + (long)zi * sCi;

  const int tM = blockIdx.y * TM;
  const int tN = blockIdx.x * TN;

  const int wave = t >> 6, lane = t & 63;
  const int wr = wave / WX, wc = wave % WX;
  const int q = lane >> 4, l16 = lane & 15;

  // Per-thread staging source pointers (16B each; LDS layout linear [rows][BK])
  const bfu* aSrc[AIT];
  const bfu* bSrc[BIT];
#pragma unroll
  for (int it = 0; it < AIT; ++it) {
    int e = (t + it * NT) * 8;
    aSrc[it] = A + (long)(tM + (e >> 5)) * lda + (e & 31);
  }
#pragma unroll
  for (int it = 0; it < BIT; ++it) {
    int e = (t + it * NT) * 8;
    bSrc[it] = B + (long)(tN + (e >> 5)) * ldb + (e & 31);
  }

  f32x4 acc[4][4] = {};

  for (int k0 = 0; k0 < K; k0 += BK) {
    __syncthreads();
#pragma unroll
    for (int it = 0; it < AIT; ++it) {
      int e = (t + it * NT) * 8;
      *(s16x8*)&As[e] = *(const s16x8*)(aSrc[it] + k0);
    }
#pragma unroll
    for (int it = 0; it < BIT; ++it) {
      int e = (t + it * NT) * 8;
      *(s16x8*)&Bs[e] = *(const s16x8*)(bSrc[it] + k0);
    }
    __syncthreads();

    s16x8 af[4], bfr[4];
#pragma unroll
    for (int i = 0; i < 4; i++)
      af[i] = *(const s16x8*)&As[(wr * 64 + i * 16 + l16) * BK + q * 8];
#pragma unroll
    for (int j = 0; j < 4; j++)
      bfr[j] = *(const s16x8*)&Bs[(wc * 64 + j * 16 + l16) * BK + q * 8];
#pragma unroll
    for (int i = 0; i < 4; i++)
#pragma unroll
      for (int j = 0; j < 4; j++)
        acc[i][j] = __builtin_amdgcn_mfma_f32_16x16x32_bf16(af[i], bfr[j], acc[i][j], 0, 0, 0);
  }

  // Epilogue. C/D layout (m89/m91): col = lane&15, row = (lane>>4)*4 + reg.
  float* Cf = (float*)Cv;
  bfu*   Cb = (bfu*)Cv;
#pragma unroll
  for (int i = 0; i < 4; i++) {
    const int row0 = tM + wr * 64 + i * 16 + q * 4;
#pragma unroll
    for (int j = 0; j < 4; j++) {
      const int col = tN + wc * 64 + j * 16 + l16;
      float bv = 0.0f;
      if (HAS_BIAS) bv = bias[col];
#pragma unroll
      for (int r = 0; r < 4; r++) {
        float v = acc[i][j][r];
        if (CAUSAL) { v *= scale; if (col > row0 + r) v = -1e30f; }
        if (HAS_BIAS) v += bv;
        if (RELU) v = fmaxf(v, 0.0f);
        long idx = cBase + (long)(row0 + r) * ldc + col;
        if (OUT_BF16) Cb[idx] = f2b(v); else Cf[idx] = v;
      }
    }
  }
}

// ---------------------------------------------------------------------------
// fp32 [R,C] -> bf16 [C,R] transpose+convert (weights)
// ---------------------------------------------------------------------------
__global__ void transpose_cvt(const float* __restrict__ src, bfu* __restrict__ dst,
                              int R, int C)
{
  __shared__ bfu tile[64 * 65];
  const int t = threadIdx.x;
  const int tc = blockIdx.x * 64, tr = blockIdx.y * 64;
#pragma unroll
  for (int i = 0; i < 16; i++) {
    int idx = t + i * 256; int r = idx >> 6, c = idx & 63;
    tile[r * 65 + c] = f2b(src[(long)(tr + r) * C + tc + c]);
  }
  __syncthreads();
#pragma unroll
  for (int i = 0; i < 16; i++) {
    int idx = t + i * 256; int r = idx >> 6, c = idx & 63;
    dst[(long)(tc + r) * R + tr + c] = tile[c * 65 + r];
  }
}

// bf16 batched transpose: src[z] [R,C] (row stride lsrc, per-z offset sSi) -> dst[z] [C,R]
__global__ void transpose_bf16_b(const bfu* __restrict__ src, long lsrc, long sSi,
                                 bfu* __restrict__ dst, long sD, int R, int C)
{
  __shared__ bfu tile[64 * 65];
  const int z = blockIdx.z;
  src += (long)z * sSi;
  dst += (long)z * sD;
  const int t = threadIdx.x;
  const int tc = blockIdx.x * 64, tr = blockIdx.y * 64;
#pragma unroll
  for (int i = 0; i < 16; i++) {
    int idx = t + i * 256; int r = idx >> 6, c = idx & 63;
    tile[r * 65 + c] = src[(long)(tr + r) * lsrc + tc + c];
  }
  __syncthreads();
#pragma unroll
  for (int i = 0; i < 16; i++) {
    int idx = t + i * 256; int r = idx >> 6, c = idx & 63;
    dst[(long)(tc + r) * R + tr + c] = tile[c * 65 + r];
  }
}

// pack one layer's q|k|v bias into [12288] fp32
__global__ void pack_qkv_bias_l(const float* __restrict__ bq, const float* __restrict__ bk,
                                const float* __restrict__ bv, float* __restrict__ outb)
{
  int j = blockIdx.x * 256 + threadIdx.x;      // 12288 total
  float v;
  if (j < 4096)       v = bq[j];
  else if (j < 8192)  v = bk[j - 4096];
  else                v = bv[j - 8192];
  outb[j] = v;
}

// block (256 threads) stats over 512 values (2/thread pre-summed by caller)
__device__ __forceinline__ void blk_stats(float s, float ss, float* red,
                                          float& mean, float& var)
{
#pragma unroll
  for (int off = 32; off; off >>= 1) { s += __shfl_down(s, off); ss += __shfl_down(ss, off); }
  int w = threadIdx.x >> 6;
  if ((threadIdx.x & 63) == 0) { red[w] = s; red[4 + w] = ss; }
  __syncthreads();
  s  = red[0] + red[1] + red[2] + red[3];
  ss = red[4] + red[5] + red[6] + red[7];
  mean = s * (1.0f / 512.0f);
  var  = ss * (1.0f / 512.0f) - mean * mean;
}

__global__ void embed_ln(const int* __restrict__ ids, const float* __restrict__ tok,
                         const float* __restrict__ pos, const float* __restrict__ g,
                         const float* __restrict__ bta, float* __restrict__ h,
                         bfu* __restrict__ hb)
{
  __shared__ float red[8];
  const int row = blockIdx.x;          // b*S + s
  const int s = row & 1023;
  const int t = threadIdx.x;
  const long base = (long)row * 512;
  const int id = ids[row];
  float x0 = tok[(long)id * 512 + t]       + pos[(long)s * 512 + t];
  float x1 = tok[(long)id * 512 + t + 256] + pos[(long)s * 512 + t + 256];
  float mean, var;
  blk_stats(x0 + x1, x0 * x0 + x1 * x1, red, mean, var);
  float rstd = rsqrtf(var + 1e-5f);
  float y0 = (x0 - mean) * rstd * g[t]       + bta[t];
  float y1 = (x1 - mean) * rstd * g[t + 256] + bta[t + 256];
  h[base + t] = y0;        h[base + t + 256] = y1;
  hb[base + t] = f2b(y0);  hb[base + t + 256] = f2b(y1);
}

__global__ void add_ln(const float* __restrict__ a, float* __restrict__ h,
                       bfu* __restrict__ hb, const float* __restrict__ g,
                       const float* __restrict__ bta)
{
  __shared__ float red[8];
  const long base = (long)blockIdx.x * 512;
  const int t = threadIdx.x;
  float x0 = a[base + t]       + h[base + t];
  float x1 = a[base + t + 256] + h[base + t + 256];
  float mean, var;
  blk_stats(x0 + x1, x0 * x0 + x1 * x1, red, mean, var);
  float rstd = rsqrtf(var + 1e-5f);
  float y0 = (x0 - mean) * rstd * g[t]       + bta[t];
  float y1 = (x1 - mean) * rstd * g[t + 256] + bta[t + 256];
  h[base + t] = y0;        h[base + t + 256] = y1;
  hb[base + t] = f2b(y0);  hb[base + t + 256] = f2b(y1);
}

// In-place causal softmax over 1024-wide bf16 rows (one block per row, fp32 math)
__global__ void softmax_inplace(bfu* __restrict__ P)
{
  __shared__ float red[8];
  const long base = (long)blockIdx.x * 1024;
  const int t = threadIdx.x;
  float v[4];
  float mx = -3e30f;
#pragma unroll
  for (int i = 0; i < 4; i++) { v[i] = b2f(P[base + t + i * 256]); mx = fmaxf(mx, v[i]); }
#pragma unroll
  for (int off = 32; off; off >>= 1) mx = fmaxf(mx, __shfl_xor(mx, off));
  int w = t >> 6;
  if ((t & 63) == 0) red[w] = mx;
  __syncthreads();
  mx = fmaxf(fmaxf(red[0], red[1]), fmaxf(red[2], red[3]));
  float e[4], sum = 0.0f;
#pragma unroll
  for (int i = 0; i < 4; i++) { e[i] = expf(v[i] - mx); sum += e[i]; }
#pragma unroll
  for (int off = 32; off; off >>= 1) sum += __shfl_xor(sum, off);
  __syncthreads();                       // red reuse
  if ((t & 63) == 0) red[4 + w] = sum;
  __syncthreads();
  sum = red[4] + red[5] + red[6] + red[7];
  float inv = 1.0f / sum;
#pragma unroll
  for (int i = 0; i < 4; i++) P[base + t + i * 256] = f2b(e[i] * inv);
}

// ---------------------------------------------------------------------------
extern "C" void kernel_launch(void* const* d_in, const int* in_sizes, int n_in,
                              void* d_out, int out_size, void* d_ws, size_t ws_size,
                              hipStream_t stream)
{
  const int*   x     = (const int*)  d_in[0];
  const float* tok   = (const float*)d_in[1];
  const float* pos   = (const float*)d_in[2];
  const float* lnig  = (const float*)d_in[3];
  const float* lnib  = (const float*)d_in[4];
  const float* Wq    = (const float*)d_in[5];
  const float* bq    = (const float*)d_in[6];
  const float* Wk    = (const float*)d_in[7];
  const float* bk    = (const float*)d_in[8];
  const float* Wv    = (const float*)d_in[9];
  const float* bv    = (const float*)d_in[10];
  const float* Wo    = (const float*)d_in[11];
  const float* bo    = (const float*)d_in[12];
  const float* ln1g  = (const float*)d_in[13];
  const float* ln1b  = (const float*)d_in[14];
  const float* W1    = (const float*)d_in[15];
  const float* b1    = (const float*)d_in[16];
  const float* W2    = (const float*)d_in[17];
  const float* b2    = (const float*)d_in[18];
  const float* ln2g  = (const float*)d_in[19];
  const float* ln2b  = (const float*)d_in[20];
  const float* Wout  = (const float*)d_in[21];
  const float* bout  = (const float*)d_in[22];

  char* wsp = (char*)d_ws;
  auto alloc = [&](size_t bytes) { char* p = wsp; wsp += (bytes + 255) & ~(size_t)255; return p; };

  // Per-layer reused weight slabs (~21 MB) + activations. Total ~115 MB.
  bfu*   qkvwT = (bfu*)  alloc(12288L * 512 * 2);       // layer l: (q|k|v)^T packed
  bfu*   woT   = (bfu*)  alloc(512L * 4096 * 2);
  bfu*   w1T   = (bfu*)  alloc(2048L * 512 * 2);
  bfu*   w2T   = (bfu*)  alloc(512L * 2048 * 2);
  bfu*   woutT = (bfu*)  alloc(512L * 512 * 2);
  float* qkvb  = (float*)alloc(12288L * 4);
  float* h     = (float*)alloc(4096L * 512 * 4);        // fp32 residual stream
  bfu*   hb    = (bfu*)  alloc(4096L * 512 * 2);        // bf16 copy (GEMM A operand)
  bfu*   qkvB  = (bfu*)  alloc(1024L * 12288 * 2);      // one batch [S][q|k|v]
  bfu*   vT    = (bfu*)  alloc(8L * 512 * 1024 * 2);    // one batch [h][d][s]
  bfu*   sc    = (bfu*)  alloc(8L * 1024 * 1024 * 2);   // scores (1 batch) / FFN hidden (all)
  bfu*   attn  = (bfu*)  alloc(4096L * 4096 * 2);       // attention output, all tokens
  float* tmp   = (float*)alloc(4096L * 512 * 4);        // pre-LN GEMM outputs

  embed_ln<<<4096, 256, 0, stream>>>(x, tok, pos, lnig, lnib, h, hb);

  transpose_cvt<<<dim3(8, 8), 256, 0, stream>>>(Wout, woutT, 512, 512);

  const float invsq = 0.044194173824159216f;  // 1/sqrt(512)

  for (int l = 0; l < 6; l++) {
    // --- stage layer l weights (bf16, transposed) ---
    transpose_cvt<<<dim3(64, 8), 256, 0, stream>>>(Wq + (long)l*512*4096, qkvwT,              512, 4096);
    transpose_cvt<<<dim3(64, 8), 256, 0, stream>>>(Wk + (long)l*512*4096, qkvwT + 4096L*512,  512, 4096);
    transpose_cvt<<<dim3(64, 8), 256, 0, stream>>>(Wv + (long)l*512*4096, qkvwT + 8192L*512,  512, 4096);
    transpose_cvt<<<dim3(8, 64), 256, 0, stream>>>(Wo + (long)l*4096*512, woT, 4096, 512);
    transpose_cvt<<<dim3(32, 8), 256, 0, stream>>>(W1 + (long)l*512*2048, w1T, 512, 2048);
    transpose_cvt<<<dim3(8, 32), 256, 0, stream>>>(W2 + (long)l*2048*512, w2T, 2048, 512);
    pack_qkv_bias_l<<<48, 256, 0, stream>>>(bq + (long)l*4096, bk + (long)l*4096,
                                            bv + (long)l*4096, qkvb);

    // --- attention, one batch at a time ---
    for (int b = 0; b < 4; b++) {
      // QKV: [1024,512] x [12288,512]^T -> qkvB [1024,12288] bf16
      gemm_bt<128,128,true,false,false,true><<<dim3(96, 8, 1), 256, 0, stream>>>(
          hb + (long)b*1024*512, 512, 0, 0, qkvwT, 512, 0, 0,
          qkvB, 12288, 0, 0, qkvb, 512, 1, 1.0f);

      // vT[h][d][s] for this batch
      transpose_bf16_b<<<dim3(8, 16, 8), 256, 0, stream>>>(
          qkvB + 8192, 12288, 512, vT, 512L*1024, 1024, 512);

      // scores = (q k^T)/sqrt(dh) + causal mask -> bf16 [h][1024][1024]
      gemm_bt<128,128,true,false,true,false><<<dim3(8, 8, 8), 256, 0, stream>>>(
          qkvB,        12288, 0, 512,
          qkvB + 4096, 12288, 0, 512,
          sc, 1024, 0, 1024L*1024, nullptr, 512, 8, invsq);

      softmax_inplace<<<8192, 256, 0, stream>>>(sc);

      // attn rows of this batch: P @ v, head h -> cols [h*512,(h+1)*512)
      gemm_bt<128,128,true,false,false,false><<<dim3(4, 8, 8), 256, 0, stream>>>(
          sc, 1024, 0, 1024L*1024,
          vT, 1024, 0, 512L*1024,
          attn + (long)b*1024*4096, 4096, 0, 512, nullptr, 1024, 8, 1.0f);
    }

    // Wo: [4096,4096] x [512,4096]^T -> tmp fp32
    gemm_bt<128,64,false,false,false,true><<<dim3(8, 32, 1), 128, 0, stream>>>(
        attn, 4096, 0, 0, woT, 4096, 0, 0,
        tmp, 512, 0, 0, bo + (long)l*512, 4096, 1, 1.0f);
    add_ln<<<4096, 256, 0, stream>>>(tmp, h, hb, ln1g + (long)l*512, ln1b + (long)l*512);

    // FFN1 (+ReLU) -> bf16 hidden (reuses sc buffer, [4096,2048])
    gemm_bt<128,128,true,true,false,true><<<dim3(16, 32, 1), 256, 0, stream>>>(
        hb, 512, 0, 0, w1T, 512, 0, 0,
        sc, 2048, 0, 0, b1 + (long)l*2048, 512, 1, 1.0f);

    // FFN2 -> tmp fp32
    gemm_bt<128,64,false,false,false,true><<<dim3(8, 32, 1), 128, 0, stream>>>(
        sc, 2048, 0, 0, w2T, 2048, 0, 0,
        tmp, 512, 0, 0, b2 + (long)l*512, 2048, 1, 1.0f);
    add_ln<<<4096, 256, 0, stream>>>(tmp, h, hb, ln2g + (long)l*512, ln2b + (long)l*512);
  }

  // final projection -> d_out fp32 [4096,512]
  gemm_bt<128,64,false,false,false,true><<<dim3(8, 32, 1), 128, 0, stream>>>(
      hb, 512, 0, 0, woutT, 512, 0, 0, (float*)d_out, 512, 0, 0, bout, 512, 1, 1.0f);
}

// Round 3
// 3227.164 us; speedup vs baseline: 1.0658x; 1.0658x over previous
//
#include <hip/hip_runtime.h>
#include <math.h>

// AutoregressiveTransformer on MI355X (gfx950).
// Round 3: occupancy fix for N=512 GEMMs (4-wave 128x64 + split-K=2 into dead
// buffers), LDS pad 32->40 shorts (conflict-free ds_read_b128), V^T via
// row-bias GEMM (no transpose kernel), fused per-layer weight prep.

typedef unsigned short bfu;                                  // raw bf16 bits
typedef short  s16x8 __attribute__((ext_vector_type(8)));    // 8 bf16 = 4 VGPR
typedef float  f32x4 __attribute__((ext_vector_type(4)));    // MFMA C/D frag

__device__ __forceinline__ bfu f2b(float f) {                // fp32 -> bf16 (RNE)
  unsigned int u = __float_as_uint(f);
  unsigned int r = (u + 0x7fffu + ((u >> 16) & 1u)) >> 16;
  return (bfu)r;
}
__device__ __forceinline__ float b2f(bfu h) {
  return __uint_as_float(((unsigned int)h) << 16);
}

// ---------------------------------------------------------------------------
// GEMM: C[m,n] = sum_k A[m,k] * Bt[n,k]  (both K-contiguous), bf16 in, fp32 acc.
// Block tile TM x TN = (WY*FI*16) x (WX*FJ*16), WY*WX waves, BK=32.
// z-batching via per-z strides (also expresses split-K: sAz=sBz=Kchunk,
// sCz=partial stride, K=Kchunk). LDS rows padded to 40 shorts (80 B):
// 16B-aligned and 2-way-max bank aliasing on ds_read_b128 / ds_write_b128.
// BIAS: 0 none, 1 per-col, 2 per-row.
// ---------------------------------------------------------------------------
template<int TM, int TN, int WY, int WX, int FI, int FJ,
         bool OUT_BF16, bool RELU, bool CAUSAL, int BIAS>
__global__ __launch_bounds__(WY * WX * 64)
void gemm_bt(const bfu* __restrict__ A, long lda, long sAz,
             const bfu* __restrict__ B, long ldb, long sBz,
             void* __restrict__ Cv, long ldc, long sCz,
             const float* __restrict__ bias,
             int K, float scale)
{
  static_assert(TM == WY * FI * 16 && TN == WX * FJ * 16, "tile mismatch");
  constexpr int BK  = 32;
  constexpr int BKP = 40;                       // padded LDS row (shorts)
  constexpr int NT  = WY * WX * 64;
  constexpr int AIT = (TM * BK) / (NT * 8);
  constexpr int BIT = (TN * BK) / (NT * 8);

  __shared__ __align__(16) bfu As[TM * BKP];
  __shared__ __align__(16) bfu Bs[TN * BKP];

  const int t = threadIdx.x;
  const int z = blockIdx.z;
  A += (long)z * sAz;
  B += (long)z * sBz;
  const long cBase = (long)z * sCz;

  const int tM = blockIdx.y * TM;
  const int tN = blockIdx.x * TN;

  const int wave = t >> 6, lane = t & 63;
  const int wr = wave / WX, wc = wave % WX;
  const int q = lane >> 4, l16 = lane & 15;

  const bfu* aSrc[AIT];
  const bfu* bSrc[BIT];
#pragma unroll
  for (int it = 0; it < AIT; ++it) {
    int e = (t + it * NT) * 8;
    aSrc[it] = A + (long)(tM + (e >> 5)) * lda + (e & 31);
  }
#pragma unroll
  for (int it = 0; it < BIT; ++it) {
    int e = (t + it * NT) * 8;
    bSrc[it] = B + (long)(tN + (e >> 5)) * ldb + (e & 31);
  }

  f32x4 acc[FI][FJ] = {};

  for (int k0 = 0; k0 < K; k0 += BK) {
    __syncthreads();
#pragma unroll
    for (int it = 0; it < AIT; ++it) {
      int e = (t + it * NT) * 8;
      *(s16x8*)&As[(e >> 5) * BKP + (e & 31)] = *(const s16x8*)(aSrc[it] + k0);
    }
#pragma unroll
    for (int it = 0; it < BIT; ++it) {
      int e = (t + it * NT) * 8;
      *(s16x8*)&Bs[(e >> 5) * BKP + (e & 31)] = *(const s16x8*)(bSrc[it] + k0);
    }
    __syncthreads();

    s16x8 af[FI], bfr[FJ];
#pragma unroll
    for (int i = 0; i < FI; i++)
      af[i] = *(const s16x8*)&As[(wr * FI * 16 + i * 16 + l16) * BKP + q * 8];
#pragma unroll
    for (int j = 0; j < FJ; j++)
      bfr[j] = *(const s16x8*)&Bs[(wc * FJ * 16 + j * 16 + l16) * BKP + q * 8];
#pragma unroll
    for (int i = 0; i < FI; i++)
#pragma unroll
      for (int j = 0; j < FJ; j++)
        acc[i][j] = __builtin_amdgcn_mfma_f32_16x16x32_bf16(af[i], bfr[j], acc[i][j], 0, 0, 0);
  }

  // Epilogue. C/D layout (m89/m91): col = lane&15, row = (lane>>4)*4 + reg.
  float* Cf = (float*)Cv;
  bfu*   Cb = (bfu*)Cv;
#pragma unroll
  for (int i = 0; i < FI; i++) {
    const int row0 = tM + wr * FI * 16 + i * 16 + q * 4;
#pragma unroll
    for (int j = 0; j < FJ; j++) {
      const int col = tN + wc * FJ * 16 + j * 16 + l16;
      float cbv = 0.0f;
      if (BIAS == 1) cbv = bias[col];
#pragma unroll
      for (int r = 0; r < 4; r++) {
        float v = acc[i][j][r];
        if (CAUSAL) { v *= scale; if (col > row0 + r) v = -1e30f; }
        if (BIAS == 1) v += cbv;
        if (BIAS == 2) v += bias[row0 + r];
        if (RELU) v = fmaxf(v, 0.0f);
        long idx = cBase + (long)(row0 + r) * ldc + col;
        if (OUT_BF16) Cb[idx] = f2b(v); else Cf[idx] = v;
      }
    }
  }
}

// ---------------------------------------------------------------------------
// fp32 [R,C] -> bf16 [C,R] transpose+convert (single matrix; used for W_out)
// ---------------------------------------------------------------------------
__global__ void transpose_cvt(const float* __restrict__ src, bfu* __restrict__ dst,
                              int R, int C)
{
  __shared__ bfu tile[64 * 65];
  const int t = threadIdx.x;
  const int tc = blockIdx.x * 64, tr = blockIdx.y * 64;
#pragma unroll
  for (int i = 0; i < 16; i++) {
    int idx = t + i * 256; int r = idx >> 6, c = idx & 63;
    tile[r * 65 + c] = f2b(src[(long)(tr + r) * C + tc + c]);
  }
  __syncthreads();
#pragma unroll
  for (int i = 0; i < 16; i++) {
    int idx = t + i * 256; int r = idx >> 6, c = idx & 63;
    dst[(long)(tc + r) * R + tr + c] = tile[c * 65 + r];
  }
}

// ---------------------------------------------------------------------------
// Fused per-layer weight prep: transposes Wq,Wk,Wv -> qkvwT, Wo -> woT,
// W1 -> w1T, W2 -> w2T, and packs q|k bias. One launch, 2592 blocks.
// ---------------------------------------------------------------------------
__global__ void prep_layer(const float* __restrict__ Wq, const float* __restrict__ Wk,
                           const float* __restrict__ Wv, const float* __restrict__ Wo,
                           const float* __restrict__ W1, const float* __restrict__ W2,
                           const float* __restrict__ bq, const float* __restrict__ bk,
                           bfu* __restrict__ qkvwT, bfu* __restrict__ woT,
                           bfu* __restrict__ w1T, bfu* __restrict__ w2T,
                           float* __restrict__ qkb)
{
  const int bid = blockIdx.x;
  const int t = threadIdx.x;

  if (bid >= 2560) {                        // bias pack: 8192 elems, 32 blocks
    int j = (bid - 2560) * 256 + t;
    qkb[j] = (j < 4096) ? bq[j] : bk[j - 4096];
    return;
  }

  const float* src; bfu* dst; int R, C, ctiles, local;
  if (bid < 512)       { src = Wq; dst = qkvwT;              R = 512;  C = 4096; ctiles = 64; local = bid; }
  else if (bid < 1024) { src = Wk; dst = qkvwT + 4096L*512;  R = 512;  C = 4096; ctiles = 64; local = bid - 512; }
  else if (bid < 1536) { src = Wv; dst = qkvwT + 8192L*512;  R = 512;  C = 4096; ctiles = 64; local = bid - 1024; }
  else if (bid < 2048) { src = Wo; dst = woT;                R = 4096; C = 512;  ctiles = 8;  local = bid - 1536; }
  else if (bid < 2304) { src = W1; dst = w1T;                R = 512;  C = 2048; ctiles = 32; local = bid - 2048; }
  else                 { src = W2; dst = w2T;                R = 2048; C = 512;  ctiles = 8;  local = bid - 2304; }
  const int tc = (local % ctiles) * 64;
  const int tr = (local / ctiles) * 64;

  __shared__ bfu tile[64 * 65];
#pragma unroll
  for (int i = 0; i < 16; i++) {
    int idx = t + i * 256; int r = idx >> 6, c = idx & 63;
    tile[r * 65 + c] = f2b(src[(long)(tr + r) * C + tc + c]);
  }
  __syncthreads();
#pragma unroll
  for (int i = 0; i < 16; i++) {
    int idx = t + i * 256; int r = idx >> 6, c = idx & 63;
    dst[(long)(tc + r) * R + tr + c] = tile[c * 65 + r];
  }
}

// block (256 threads) stats over 512 values (2/thread pre-summed by caller)
__device__ __forceinline__ void blk_stats(float s, float ss, float* red,
                                          float& mean, float& var)
{
#pragma unroll
  for (int off = 32; off; off >>= 1) { s += __shfl_down(s, off); ss += __shfl_down(ss, off); }
  int w = threadIdx.x >> 6;
  if ((threadIdx.x & 63) == 0) { red[w] = s; red[4 + w] = ss; }
  __syncthreads();
  s  = red[0] + red[1] + red[2] + red[3];
  ss = red[4] + red[5] + red[6] + red[7];
  mean = s * (1.0f / 512.0f);
  var  = ss * (1.0f / 512.0f) - mean * mean;
}

__global__ void embed_ln(const int* __restrict__ ids, const float* __restrict__ tok,
                         const float* __restrict__ pos, const float* __restrict__ g,
                         const float* __restrict__ bta, float* __restrict__ h,
                         bfu* __restrict__ hb)
{
  __shared__ float red[8];
  const int row = blockIdx.x;          // b*S + s
  const int s = row & 1023;
  const int t = threadIdx.x;
  const long base = (long)row * 512;
  const int id = ids[row];
  float x0 = tok[(long)id * 512 + t]       + pos[(long)s * 512 + t];
  float x1 = tok[(long)id * 512 + t + 256] + pos[(long)s * 512 + t + 256];
  float mean, var;
  blk_stats(x0 + x1, x0 * x0 + x1 * x1, red, mean, var);
  float rstd = rsqrtf(var + 1e-5f);
  float y0 = (x0 - mean) * rstd * g[t]       + bta[t];
  float y1 = (x1 - mean) * rstd * g[t + 256] + bta[t + 256];
  h[base + t] = y0;        h[base + t + 256] = y1;
  hb[base + t] = f2b(y0);  hb[base + t + 256] = f2b(y1);
}

// x = p[i] + p[i+ps] + bias[col] + h[i]  -> LN -> h, hb   (split-K reducer + LN)
__global__ void add_ln_red(const float* __restrict__ p, long ps,
                           const float* __restrict__ bias,
                           float* __restrict__ h, bfu* __restrict__ hb,
                           const float* __restrict__ g, const float* __restrict__ bta)
{
  __shared__ float red[8];
  const long base = (long)blockIdx.x * 512;
  const int t = threadIdx.x;
  float x0 = p[base + t]       + p[base + ps + t]       + bias[t]       + h[base + t];
  float x1 = p[base + t + 256] + p[base + ps + t + 256] + bias[t + 256] + h[base + t + 256];
  float mean, var;
  blk_stats(x0 + x1, x0 * x0 + x1 * x1, red, mean, var);
  float rstd = rsqrtf(var + 1e-5f);
  float y0 = (x0 - mean) * rstd * g[t]       + bta[t];
  float y1 = (x1 - mean) * rstd * g[t + 256] + bta[t + 256];
  h[base + t] = y0;        h[base + t + 256] = y1;
  hb[base + t] = f2b(y0);  hb[base + t + 256] = f2b(y1);
}

// out[i] = p[i] + p[i+ps] + bias[col]  (final projection reducer)
__global__ void out_red(const float* __restrict__ p, long ps,
                        const float* __restrict__ bias, float* __restrict__ out)
{
  const long base = (long)blockIdx.x * 512;
  const int t = threadIdx.x;
  out[base + t]       = p[base + t]       + p[base + ps + t]       + bias[t];
  out[base + t + 256] = p[base + t + 256] + p[base + ps + t + 256] + bias[t + 256];
}

// In-place causal softmax over 1024-wide bf16 rows (one block per row, fp32 math)
__global__ void softmax_inplace(bfu* __restrict__ P)
{
  __shared__ float red[8];
  const long base = (long)blockIdx.x * 1024;
  const int t = threadIdx.x;
  float v[4];
  float mx = -3e30f;
#pragma unroll
  for (int i = 0; i < 4; i++) { v[i] = b2f(P[base + t + i * 256]); mx = fmaxf(mx, v[i]); }
#pragma unroll
  for (int off = 32; off; off >>= 1) mx = fmaxf(mx, __shfl_xor(mx, off));
  int w = t >> 6;
  if ((t & 63) == 0) red[w] = mx;
  __syncthreads();
  mx = fmaxf(fmaxf(red[0], red[1]), fmaxf(red[2], red[3]));
  float e[4], sum = 0.0f;
#pragma unroll
  for (int i = 0; i < 4; i++) { e[i] = expf(v[i] - mx); sum += e[i]; }
#pragma unroll
  for (int off = 32; off; off >>= 1) sum += __shfl_xor(sum, off);
  __syncthreads();
  if ((t & 63) == 0) red[4 + w] = sum;
  __syncthreads();
  sum = red[4] + red[5] + red[6] + red[7];
  float inv = 1.0f / sum;
#pragma unroll
  for (int i = 0; i < 4; i++) P[base + t + i * 256] = f2b(e[i] * inv);
}

// ---------------------------------------------------------------------------
extern "C" void kernel_launch(void* const* d_in, const int* in_sizes, int n_in,
                              void* d_out, int out_size, void* d_ws, size_t ws_size,
                              hipStream_t stream)
{
  const int*   x     = (const int*)  d_in[0];
  const float* tok   = (const float*)d_in[1];
  const float* pos   = (const float*)d_in[2];
  const float* lnig  = (const float*)d_in[3];
  const float* lnib  = (const float*)d_in[4];
  const float* Wq    = (const float*)d_in[5];
  const float* bq    = (const float*)d_in[6];
  const float* Wk    = (const float*)d_in[7];
  const float* bk    = (const float*)d_in[8];
  const float* Wv    = (const float*)d_in[9];
  const float* bv    = (const float*)d_in[10];
  const float* Wo    = (const float*)d_in[11];
  const float* bo    = (const float*)d_in[12];
  const float* ln1g  = (const float*)d_in[13];
  const float* ln1b  = (const float*)d_in[14];
  const float* W1    = (const float*)d_in[15];
  const float* b1    = (const float*)d_in[16];
  const float* W2    = (const float*)d_in[17];
  const float* b2    = (const float*)d_in[18];
  const float* ln2g  = (const float*)d_in[19];
  const float* ln2b  = (const float*)d_in[20];
  const float* Wout  = (const float*)d_in[21];
  const float* bout  = (const float*)d_in[22];

  char* wsp = (char*)d_ws;
  auto alloc = [&](size_t bytes) { char* p = wsp; wsp += (bytes + 255) & ~(size_t)255; return p; };

  // ~110 MB total; all buffers written before read every call.
  bfu*   qkvwT = (bfu*)  alloc(12288L * 512 * 2);       // layer l: (q|k|v)^T packed
  bfu*   woT   = (bfu*)  alloc(512L * 4096 * 2);
  bfu*   w1T   = (bfu*)  alloc(2048L * 512 * 2);
  bfu*   w2T   = (bfu*)  alloc(512L * 2048 * 2);
  bfu*   woutT = (bfu*)  alloc(512L * 512 * 2);
  float* qkb   = (float*)alloc(8192L * 4);
  float* h     = (float*)alloc(4096L * 512 * 4);        // fp32 residual stream
  bfu*   hb    = (bfu*)  alloc(4096L * 512 * 2);        // bf16 copy (GEMM A operand)
  bfu*   qkB   = (bfu*)  alloc(1024L * 8192 * 2);       // one batch [S][q|k]; also fp32 split-K partials (FFN2/final)
  bfu*   vT    = (bfu*)  alloc(8L * 512 * 1024 * 2);    // one batch [h][d][s]
  bfu*   sc    = (bfu*)  alloc(8L * 1024 * 1024 * 2);   // scores (1 batch) / Wo partials / FFN hidden
  bfu*   attn  = (bfu*)  alloc(4096L * 4096 * 2);       // attention output, all tokens

  embed_ln<<<4096, 256, 0, stream>>>(x, tok, pos, lnig, lnib, h, hb);
  transpose_cvt<<<dim3(8, 8), 256, 0, stream>>>(Wout, woutT, 512, 512);

  const float invsq = 0.044194173824159216f;  // 1/sqrt(512)
  const long  PSTR  = 4096L * 512;            // split-K partial stride (floats)

  for (int l = 0; l < 6; l++) {
    prep_layer<<<2592, 256, 0, stream>>>(
        Wq + (long)l*512*4096, Wk + (long)l*512*4096, Wv + (long)l*512*4096,
        Wo + (long)l*4096*512, W1 + (long)l*512*2048, W2 + (long)l*2048*512,
        bq + (long)l*4096, bk + (long)l*4096,
        qkvwT, woT, w1T, w2T, qkb);

    for (int b = 0; b < 4; b++) {
      const bfu* hbB = hb + (long)b * 1024 * 512;

      // q|k: [1024,512] x [8192,512]^T -> qkB [1024,8192] bf16 (+bias)
      gemm_bt<128,128,2,2,4,4,true,false,false,1><<<dim3(64, 8, 1), 256, 0, stream>>>(
          hbB, 512, 0, qkvwT, 512, 0, qkB, 8192, 0, qkb, 512, 1.0f);

      // vT[h][d][s] = Wv^T @ h^T (+row bias): [4096,512] x [1024,512]^T
      gemm_bt<128,128,2,2,4,4,true,false,false,2><<<dim3(8, 32, 1), 256, 0, stream>>>(
          qkvwT + 8192L*512, 512, 0, hbB, 512, 0, vT, 1024, 0,
          bv + (long)l*4096, 512, 1.0f);

      // scores = (q k^T)/sqrt(dh) + causal mask -> bf16 [h][1024][1024]
      gemm_bt<128,128,2,2,4,4,true,false,true,0><<<dim3(8, 8, 8), 256, 0, stream>>>(
          qkB,        8192, 512,
          qkB + 4096, 8192, 512,
          sc, 1024, 1024L*1024, nullptr, 512, invsq);

      softmax_inplace<<<8192, 256, 0, stream>>>(sc);

      // attn[b] cols h*512.. : P @ v  (per-head, 4-wave 128x64)
      gemm_bt<128,64,2,2,4,2,true,false,false,0><<<dim3(8, 8, 8), 256, 0, stream>>>(
          sc, 1024, 1024L*1024,
          vT, 1024, 512L*1024,
          attn + (long)b*1024*4096, 4096, 512, nullptr, 1024, 1.0f);
    }

    // Wo: [4096,4096] x [512,4096]^T, split-K=2 -> fp32 partials in sc
    gemm_bt<128,64,2,2,4,2,false,false,false,0><<<dim3(8, 32, 2), 256, 0, stream>>>(
        attn, 4096, 2048, woT, 4096, 2048,
        (float*)sc, 512, PSTR, nullptr, 2048, 1.0f);
    add_ln_red<<<4096, 256, 0, stream>>>((float*)sc, PSTR, bo + (long)l*512,
                                         h, hb, ln1g + (long)l*512, ln1b + (long)l*512);

    // FFN1 (+ReLU) -> bf16 hidden in sc [4096,2048]
    gemm_bt<128,128,2,2,4,4,true,true,false,1><<<dim3(16, 32, 1), 256, 0, stream>>>(
        hb, 512, 0, w1T, 512, 0, sc, 2048, 0, b1 + (long)l*2048, 512, 1.0f);

    // FFN2: [4096,2048] x [512,2048]^T, split-K=2 -> fp32 partials in qkB
    gemm_bt<128,64,2,2,4,2,false,false,false,0><<<dim3(8, 32, 2), 256, 0, stream>>>(
        sc, 2048, 1024, w2T, 2048, 1024,
        (float*)qkB, 512, PSTR, nullptr, 1024, 1.0f);
    add_ln_red<<<4096, 256, 0, stream>>>((float*)qkB, PSTR, b2 + (long)l*512,
                                         h, hb, ln2g + (long)l*512, ln2b + (long)l*512);
  }

  // final projection: [4096,512] x [512,512]^T, split-K=2 -> partials in qkB
  gemm_bt<128,64,2,2,4,2,false,false,false,0><<<dim3(8, 32, 2), 256, 0, stream>>>(
      hb, 512, 256, woutT, 512, 256,
      (float*)qkB, 512, PSTR, nullptr, 256, 1.0f);
  out_red<<<4096, 256, 0, stream>>>((float*)qkB, PSTR, bout, (float*)d_out);
}

// Round 4
// 2901.793 us; speedup vs baseline: 1.1853x; 1.1121x over previous
//
#include <hip/hip_runtime.h>
#include <math.h>

// AutoregressiveTransformer on MI355X (gfx950).
// Round 4: global_load_lds width=16 staging (m97 pattern) + XOR-swizzled LDS
// columns (conflict-lite ds_read_b128 without padding) + XCD-cluster block
// swizzle for L2 operand reuse (cuts Wo/FFN2 A re-fetch).

typedef unsigned short bfu;                                  // raw bf16 bits
typedef short  s16x8 __attribute__((ext_vector_type(8)));    // 8 bf16 = 4 VGPR
typedef float  f32x4 __attribute__((ext_vector_type(4)));    // MFMA C/D frag

__device__ __forceinline__ bfu f2b(float f) {                // fp32 -> bf16 (RNE)
  unsigned int u = __float_as_uint(f);
  unsigned int r = (u + 0x7fffu + ((u >> 16) & 1u)) >> 16;
  return (bfu)r;
}
__device__ __forceinline__ float b2f(bfu h) {
  return __uint_as_float(((unsigned int)h) << 16);
}

// async global->LDS, 16 B per lane; LDS dest = wave-uniform base + lane*16
__device__ __forceinline__ void async16(const bfu* g, bfu* l) {
  __builtin_amdgcn_global_load_lds(
      (const __attribute__((address_space(1))) void*)g,
      (__attribute__((address_space(3))) void*)l, 16, 0, 0);
}

// ---------------------------------------------------------------------------
// GEMM: C[m,n] = sum_k A[m,k] * Bt[n,k]  (both K-contiguous), bf16 in, fp32 acc.
// Block tile TM x TN = (WY*FI*16) x (WX*FJ*16), WY*WX waves, BK=32.
// Staging: global_load_lds dwordx4 (async, no VGPR round-trip). LDS layout
// row-major [row][32] with XOR column-group swizzle grp^=((row>>1)&3) encoded
// in the staging GLOBAL address (keeps lane-contiguous LDS dest).
// XCD-cluster swizzle: flat%8 = XCD (dispatch heuristic); each XCD gets a
// cluster of cx x-tiles * (perXcd/cx) yz-tiles -> operand stripes stay in its L2.
// z expresses batching or split-K via per-z strides. BIAS: 0 none,1 col,2 row.
// ---------------------------------------------------------------------------
template<int TM, int TN, int WY, int WX, int FI, int FJ,
         bool OUT_BF16, bool RELU, bool CAUSAL, int BIAS>
__global__ __launch_bounds__(WY * WX * 64)
void gemm_bt(const bfu* __restrict__ A, long lda, long sAz,
             const bfu* __restrict__ B, long ldb, long sBz,
             void* __restrict__ Cv, long ldc, long sCz,
             const float* __restrict__ bias,
             int K, float scale, int cx)
{
  static_assert(TM == WY * FI * 16 && TN == WX * FJ * 16, "tile mismatch");
  constexpr int BK = 32;
  constexpr int NW = WY * WX;
  constexpr int AI = TM / (16 * NW);              // A staging instrs/wave
  constexpr int BI = TN / (16 * NW);              // B staging instrs/wave

  __shared__ __align__(16) bfu As[TM * BK];
  __shared__ __align__(16) bfu Bs[TN * BK];

  // ---- XCD-cluster tile decode (requires total%8==0, cx|perXcd, cx|NX) ----
  const int NX = gridDim.x, NY = gridDim.y;
  const int flat  = blockIdx.x + NX * (blockIdx.y + NY * blockIdx.z);
  const int total = NX * NY * gridDim.z;
  const int xcd = flat & 7, idx = flat >> 3;
  const int perX = total >> 3;
  const int clX  = NX / cx;                       // clusters along x
  const int ry   = perX / cx;                     // yz-tiles per cluster
  const int tx   = (xcd % clX) * cx + idx % cx;
  const int yz   = (xcd / clX) * ry + idx / cx;
  const int ty   = yz % NY, tz = yz / NY;

  A += (long)tz * sAz;
  B += (long)tz * sBz;
  const long cBase = (long)tz * sCz;
  const int tM = ty * TM;
  const int tN = tx * TN;

  const int t = threadIdx.x;
  const int wave = t >> 6, lane = t & 63;
  const int wr = wave / WX, wc = wave % WX;
  const int q = lane >> 4, l16 = lane & 15;

  // ---- staging addresses (lane -> row lane/4, col-group (lane&3)^swz(row)) ----
  const bfu* aG[AI]; bfu* aL[AI];
  const bfu* bG[BI]; bfu* bL[BI];
#pragma unroll
  for (int i2 = 0; i2 < AI; i2++) {
    const int rb = (i2 * NW + wave) * 16;
    const int r  = rb + (lane >> 2);
    const int g  = (lane & 3) ^ ((r >> 1) & 3);
    aG[i2] = A + (long)(tM + r) * lda + g * 8;
    aL[i2] = &As[rb * BK];
  }
#pragma unroll
  for (int i2 = 0; i2 < BI; i2++) {
    const int rb = (i2 * NW + wave) * 16;
    const int r  = rb + (lane >> 2);
    const int g  = (lane & 3) ^ ((r >> 1) & 3);
    bG[i2] = B + (long)(tN + r) * ldb + g * 8;
    bL[i2] = &Bs[rb * BK];
  }

  // ---- fragment LDS offsets (swizzled; k-invariant) ----
  int aOff[FI], bOff[FJ];
#pragma unroll
  for (int i = 0; i < FI; i++) {
    const int r = wr * FI * 16 + i * 16 + l16;
    aOff[i] = r * BK + ((q ^ ((r >> 1) & 3)) * 8);
  }
#pragma unroll
  for (int j = 0; j < FJ; j++) {
    const int r = wc * FJ * 16 + j * 16 + l16;
    bOff[j] = r * BK + ((q ^ ((r >> 1) & 3)) * 8);
  }

  f32x4 acc[FI][FJ] = {};

  for (int k0 = 0; k0 < K; k0 += BK) {
    __syncthreads();
#pragma unroll
    for (int i2 = 0; i2 < AI; i2++) async16(aG[i2] + k0, aL[i2]);
#pragma unroll
    for (int i2 = 0; i2 < BI; i2++) async16(bG[i2] + k0, bL[i2]);
    __syncthreads();

    s16x8 af[FI], bfr[FJ];
#pragma unroll
    for (int i = 0; i < FI; i++) af[i]  = *(const s16x8*)&As[aOff[i]];
#pragma unroll
    for (int j = 0; j < FJ; j++) bfr[j] = *(const s16x8*)&Bs[bOff[j]];
#pragma unroll
    for (int i = 0; i < FI; i++)
#pragma unroll
      for (int j = 0; j < FJ; j++)
        acc[i][j] = __builtin_amdgcn_mfma_f32_16x16x32_bf16(af[i], bfr[j], acc[i][j], 0, 0, 0);
  }

  // Epilogue. C/D layout (m89/m91): col = lane&15, row = (lane>>4)*4 + reg.
  float* Cf = (float*)Cv;
  bfu*   Cb = (bfu*)Cv;
#pragma unroll
  for (int i = 0; i < FI; i++) {
    const int row0 = tM + wr * FI * 16 + i * 16 + q * 4;
#pragma unroll
    for (int j = 0; j < FJ; j++) {
      const int col = tN + wc * FJ * 16 + j * 16 + l16;
      float cbv = 0.0f;
      if (BIAS == 1) cbv = bias[col];
#pragma unroll
      for (int r = 0; r < 4; r++) {
        float v = acc[i][j][r];
        if (CAUSAL) { v *= scale; if (col > row0 + r) v = -1e30f; }
        if (BIAS == 1) v += cbv;
        if (BIAS == 2) v += bias[row0 + r];
        if (RELU) v = fmaxf(v, 0.0f);
        long idxc = cBase + (long)(row0 + r) * ldc + col;
        if (OUT_BF16) Cb[idxc] = f2b(v); else Cf[idxc] = v;
      }
    }
  }
}

// ---------------------------------------------------------------------------
// fp32 [R,C] -> bf16 [C,R] transpose+convert (single matrix; used for W_out)
// ---------------------------------------------------------------------------
__global__ void transpose_cvt(const float* __restrict__ src, bfu* __restrict__ dst,
                              int R, int C)
{
  __shared__ bfu tile[64 * 65];
  const int t = threadIdx.x;
  const int tc = blockIdx.x * 64, tr = blockIdx.y * 64;
#pragma unroll
  for (int i = 0; i < 16; i++) {
    int idx = t + i * 256; int r = idx >> 6, c = idx & 63;
    tile[r * 65 + c] = f2b(src[(long)(tr + r) * C + tc + c]);
  }
  __syncthreads();
#pragma unroll
  for (int i = 0; i < 16; i++) {
    int idx = t + i * 256; int r = idx >> 6, c = idx & 63;
    dst[(long)(tc + r) * R + tr + c] = tile[c * 65 + r];
  }
}

// ---------------------------------------------------------------------------
// Fused per-layer weight prep: Wq,Wk,Wv -> qkvwT, Wo -> woT, W1 -> w1T,
// W2 -> w2T, packs q|k bias. One launch, 2592 blocks.
// ---------------------------------------------------------------------------
__global__ void prep_layer(const float* __restrict__ Wq, const float* __restrict__ Wk,
                           const float* __restrict__ Wv, const float* __restrict__ Wo,
                           const float* __restrict__ W1, const float* __restrict__ W2,
                           const float* __restrict__ bq, const float* __restrict__ bk,
                           bfu* __restrict__ qkvwT, bfu* __restrict__ woT,
                           bfu* __restrict__ w1T, bfu* __restrict__ w2T,
                           float* __restrict__ qkb)
{
  const int bid = blockIdx.x;
  const int t = threadIdx.x;

  if (bid >= 2560) {                        // bias pack: 8192 elems, 32 blocks
    int j = (bid - 2560) * 256 + t;
    qkb[j] = (j < 4096) ? bq[j] : bk[j - 4096];
    return;
  }

  const float* src; bfu* dst; int R, C, ctiles, local;
  if (bid < 512)       { src = Wq; dst = qkvwT;              R = 512;  C = 4096; ctiles = 64; local = bid; }
  else if (bid < 1024) { src = Wk; dst = qkvwT + 4096L*512;  R = 512;  C = 4096; ctiles = 64; local = bid - 512; }
  else if (bid < 1536) { src = Wv; dst = qkvwT + 8192L*512;  R = 512;  C = 4096; ctiles = 64; local = bid - 1024; }
  else if (bid < 2048) { src = Wo; dst = woT;                R = 4096; C = 512;  ctiles = 8;  local = bid - 1536; }
  else if (bid < 2304) { src = W1; dst = w1T;                R = 512;  C = 2048; ctiles = 32; local = bid - 2048; }
  else                 { src = W2; dst = w2T;                R = 2048; C = 512;  ctiles = 8;  local = bid - 2304; }
  const int tc = (local % ctiles) * 64;
  const int tr = (local / ctiles) * 64;

  __shared__ bfu tile[64 * 65];
#pragma unroll
  for (int i = 0; i < 16; i++) {
    int idx = t + i * 256; int r = idx >> 6, c = idx & 63;
    tile[r * 65 + c] = f2b(src[(long)(tr + r) * C + tc + c]);
  }
  __syncthreads();
#pragma unroll
  for (int i = 0; i < 16; i++) {
    int idx = t + i * 256; int r = idx >> 6, c = idx & 63;
    dst[(long)(tc + r) * R + tr + c] = tile[c * 65 + r];
  }
}

// block (256 threads) stats over 512 values (2/thread pre-summed by caller)
__device__ __forceinline__ void blk_stats(float s, float ss, float* red,
                                          float& mean, float& var)
{
#pragma unroll
  for (int off = 32; off; off >>= 1) { s += __shfl_down(s, off); ss += __shfl_down(ss, off); }
  int w = threadIdx.x >> 6;
  if ((threadIdx.x & 63) == 0) { red[w] = s; red[4 + w] = ss; }
  __syncthreads();
  s  = red[0] + red[1] + red[2] + red[3];
  ss = red[4] + red[5] + red[6] + red[7];
  mean = s * (1.0f / 512.0f);
  var  = ss * (1.0f / 512.0f) - mean * mean;
}

__global__ void embed_ln(const int* __restrict__ ids, const float* __restrict__ tok,
                         const float* __restrict__ pos, const float* __restrict__ g,
                         const float* __restrict__ bta, float* __restrict__ h,
                         bfu* __restrict__ hb)
{
  __shared__ float red[8];
  const int row = blockIdx.x;          // b*S + s
  const int s = row & 1023;
  const int t = threadIdx.x;
  const long base = (long)row * 512;
  const int id = ids[row];
  float x0 = tok[(long)id * 512 + t]       + pos[(long)s * 512 + t];
  float x1 = tok[(long)id * 512 + t + 256] + pos[(long)s * 512 + t + 256];
  float mean, var;
  blk_stats(x0 + x1, x0 * x0 + x1 * x1, red, mean, var);
  float rstd = rsqrtf(var + 1e-5f);
  float y0 = (x0 - mean) * rstd * g[t]       + bta[t];
  float y1 = (x1 - mean) * rstd * g[t + 256] + bta[t + 256];
  h[base + t] = y0;        h[base + t + 256] = y1;
  hb[base + t] = f2b(y0);  hb[base + t + 256] = f2b(y1);
}

// x = p[i] + p[i+ps] + bias[col] + h[i]  -> LN -> h, hb   (split-K reducer + LN)
__global__ void add_ln_red(const float* __restrict__ p, long ps,
                           const float* __restrict__ bias,
                           float* __restrict__ h, bfu* __restrict__ hb,
                           const float* __restrict__ g, const float* __restrict__ bta)
{
  __shared__ float red[8];
  const long base = (long)blockIdx.x * 512;
  const int t = threadIdx.x;
  float x0 = p[base + t]       + p[base + ps + t]       + bias[t]       + h[base + t];
  float x1 = p[base + t + 256] + p[base + ps + t + 256] + bias[t + 256] + h[base + t + 256];
  float mean, var;
  blk_stats(x0 + x1, x0 * x0 + x1 * x1, red, mean, var);
  float rstd = rsqrtf(var + 1e-5f);
  float y0 = (x0 - mean) * rstd * g[t]       + bta[t];
  float y1 = (x1 - mean) * rstd * g[t + 256] + bta[t + 256];
  h[base + t] = y0;        h[base + t + 256] = y1;
  hb[base + t] = f2b(y0);  hb[base + t + 256] = f2b(y1);
}

// out[i] = p[i] + p[i+ps] + bias[col]  (final projection reducer)
__global__ void out_red(const float* __restrict__ p, long ps,
                        const float* __restrict__ bias, float* __restrict__ out)
{
  const long base = (long)blockIdx.x * 512;
  const int t = threadIdx.x;
  out[base + t]       = p[base + t]       + p[base + ps + t]       + bias[t];
  out[base + t + 256] = p[base + t + 256] + p[base + ps + t + 256] + bias[t + 256];
}

// In-place causal softmax over 1024-wide bf16 rows (one block per row, fp32 math)
__global__ void softmax_inplace(bfu* __restrict__ P)
{
  __shared__ float red[8];
  const long base = (long)blockIdx.x * 1024;
  const int t = threadIdx.x;
  float v[4];
  float mx = -3e30f;
#pragma unroll
  for (int i = 0; i < 4; i++) { v[i] = b2f(P[base + t + i * 256]); mx = fmaxf(mx, v[i]); }
#pragma unroll
  for (int off = 32; off; off >>= 1) mx = fmaxf(mx, __shfl_xor(mx, off));
  int w = t >> 6;
  if ((t & 63) == 0) red[w] = mx;
  __syncthreads();
  mx = fmaxf(fmaxf(red[0], red[1]), fmaxf(red[2], red[3]));
  float e[4], sum = 0.0f;
#pragma unroll
  for (int i = 0; i < 4; i++) { e[i] = expf(v[i] - mx); sum += e[i]; }
#pragma unroll
  for (int off = 32; off; off >>= 1) sum += __shfl_xor(sum, off);
  __syncthreads();
  if ((t & 63) == 0) red[4 + w] = sum;
  __syncthreads();
  sum = red[4] + red[5] + red[6] + red[7];
  float inv = 1.0f / sum;
#pragma unroll
  for (int i = 0; i < 4; i++) P[base + t + i * 256] = f2b(e[i] * inv);
}

// ---------------------------------------------------------------------------
extern "C" void kernel_launch(void* const* d_in, const int* in_sizes, int n_in,
                              void* d_out, int out_size, void* d_ws, size_t ws_size,
                              hipStream_t stream)
{
  const int*   x     = (const int*)  d_in[0];
  const float* tok   = (const float*)d_in[1];
  const float* pos   = (const float*)d_in[2];
  const float* lnig  = (const float*)d_in[3];
  const float* lnib  = (const float*)d_in[4];
  const float* Wq    = (const float*)d_in[5];
  const float* bq    = (const float*)d_in[6];
  const float* Wk    = (const float*)d_in[7];
  const float* bk    = (const float*)d_in[8];
  const float* Wv    = (const float*)d_in[9];
  const float* bv    = (const float*)d_in[10];
  const float* Wo    = (const float*)d_in[11];
  const float* bo    = (const float*)d_in[12];
  const float* ln1g  = (const float*)d_in[13];
  const float* ln1b  = (const float*)d_in[14];
  const float* W1    = (const float*)d_in[15];
  const float* b1    = (const float*)d_in[16];
  const float* W2    = (const float*)d_in[17];
  const float* b2    = (const float*)d_in[18];
  const float* ln2g  = (const float*)d_in[19];
  const float* ln2b  = (const float*)d_in[20];
  const float* Wout  = (const float*)d_in[21];
  const float* bout  = (const float*)d_in[22];

  char* wsp = (char*)d_ws;
  auto alloc = [&](size_t bytes) { char* p = wsp; wsp += (bytes + 255) & ~(size_t)255; return p; };

  // ~110 MB total; all buffers written before read every call.
  bfu*   qkvwT = (bfu*)  alloc(12288L * 512 * 2);       // layer l: (q|k|v)^T packed
  bfu*   woT   = (bfu*)  alloc(512L * 4096 * 2);
  bfu*   w1T   = (bfu*)  alloc(2048L * 512 * 2);
  bfu*   w2T   = (bfu*)  alloc(512L * 2048 * 2);
  bfu*   woutT = (bfu*)  alloc(512L * 512 * 2);
  float* qkb   = (float*)alloc(8192L * 4);
  float* h     = (float*)alloc(4096L * 512 * 4);        // fp32 residual stream
  bfu*   hb    = (bfu*)  alloc(4096L * 512 * 2);        // bf16 copy (GEMM A operand)
  bfu*   qkB   = (bfu*)  alloc(1024L * 8192 * 2);       // one batch [S][q|k]; also fp32 split-K partials
  bfu*   vT    = (bfu*)  alloc(8L * 512 * 1024 * 2);    // one batch [h][d][s]
  bfu*   sc    = (bfu*)  alloc(8L * 1024 * 1024 * 2);   // scores (1 batch) / Wo partials / FFN hidden
  bfu*   attn  = (bfu*)  alloc(4096L * 4096 * 2);       // attention output, all tokens

  embed_ln<<<4096, 256, 0, stream>>>(x, tok, pos, lnig, lnib, h, hb);
  transpose_cvt<<<dim3(8, 8), 256, 0, stream>>>(Wout, woutT, 512, 512);

  const float invsq = 0.044194173824159216f;  // 1/sqrt(512)
  const long  PSTR  = 4096L * 512;            // split-K partial stride (floats)

  for (int l = 0; l < 6; l++) {
    prep_layer<<<2592, 256, 0, stream>>>(
        Wq + (long)l*512*4096, Wk + (long)l*512*4096, Wv + (long)l*512*4096,
        Wo + (long)l*4096*512, W1 + (long)l*512*2048, W2 + (long)l*2048*512,
        bq + (long)l*4096, bk + (long)l*4096,
        qkvwT, woT, w1T, w2T, qkb);

    for (int b = 0; b < 4; b++) {
      const bfu* hbB = hb + (long)b * 1024 * 512;

      // q|k: [1024,512] x [8192,512]^T -> qkB [1024,8192] bf16 (+bias)
      // cluster 8x*8y per XCD: A (1MB) + B x-stripes fetched ~once per XCD
      gemm_bt<128,128,2,2,4,4,true,false,false,1><<<dim3(64, 8, 1), 256, 0, stream>>>(
          hbB, 512, 0, qkvwT, 512, 0, qkB, 8192, 0, qkb, 512, 1.0f, 8);

      // vT[h][d][s] = Wv^T @ h^T (+row bias): [4096,512] x [1024,512]^T
      gemm_bt<128,128,2,2,4,4,true,false,false,2><<<dim3(8, 32, 1), 256, 0, stream>>>(
          qkvwT + 8192L*512, 512, 0, hbB, 512, 0, vT, 1024, 0,
          bv + (long)l*4096, 512, 1.0f, 8);

      // scores = (q k^T)/sqrt(dh) + causal mask -> bf16 [h][1024][1024]
      // cluster = one head per XCD (q,k of that head stay in L2)
      gemm_bt<128,128,2,2,4,4,true,false,true,0><<<dim3(8, 8, 8), 256, 0, stream>>>(
          qkB,        8192, 512,
          qkB + 4096, 8192, 512,
          sc, 1024, 1024L*1024, nullptr, 512, invsq, 8);

      softmax_inplace<<<8192, 256, 0, stream>>>(sc);

      // attn[b] cols h*512.. : P @ v  (per-head)
      gemm_bt<128,64,2,2,4,2,true,false,false,0><<<dim3(8, 8, 8), 256, 0, stream>>>(
          sc, 1024, 1024L*1024,
          vT, 1024, 512L*1024,
          attn + (long)b*1024*4096, 4096, 512, nullptr, 1024, 1.0f, 8);
    }

    // Wo: [4096,4096] x [512,4096]^T, split-K=2 -> fp32 partials in sc
    // full-x cluster: each XCD owns 8 y-stripes -> A (32MB) fetched once total
    gemm_bt<128,64,2,2,4,2,false,false,false,0><<<dim3(8, 32, 2), 256, 0, stream>>>(
        attn, 4096, 2048, woT, 4096, 2048,
        (float*)sc, 512, PSTR, nullptr, 2048, 1.0f, 8);
    add_ln_red<<<4096, 256, 0, stream>>>((float*)sc, PSTR, bo + (long)l*512,
                                         h, hb, ln1g + (long)l*512, ln1b + (long)l*512);

    // FFN1 (+ReLU) -> bf16 hidden in sc [4096,2048]
    gemm_bt<128,128,2,2,4,4,true,true,false,1><<<dim3(16, 32, 1), 256, 0, stream>>>(
        hb, 512, 0, w1T, 512, 0, sc, 2048, 0, b1 + (long)l*2048, 512, 1.0f, 16);

    // FFN2: [4096,2048] x [512,2048]^T, split-K=2 -> fp32 partials in qkB
    gemm_bt<128,64,2,2,4,2,false,false,false,0><<<dim3(8, 32, 2), 256, 0, stream>>>(
        sc, 2048, 1024, w2T, 2048, 1024,
        (float*)qkB, 512, PSTR, nullptr, 1024, 1.0f, 8);
    add_ln_red<<<4096, 256, 0, stream>>>((float*)qkB, PSTR, b2 + (long)l*512,
                                         h, hb, ln2g + (long)l*512, ln2b + (long)l*512);
  }

  // final projection: [4096,512] x [512,512]^T, split-K=2 -> partials in qkB
  gemm_bt<128,64,2,2,4,2,false,false,false,0><<<dim3(8, 32, 2), 256, 0, stream>>>(
      hb, 512, 256, woutT, 512, 256,
      (float*)qkB, 512, PSTR, nullptr, 256, 1.0f, 8);
  out_red<<<4096, 256, 0, stream>>>((float*)qkB, PSTR, bout, (float*)d_out);
}

// Round 5
// 2041.881 us; speedup vs baseline: 1.6845x; 1.4211x over previous
//
#include <hip/hip_runtime.h>
#include <math.h>

// AutoregressiveTransformer on MI355X (gfx950).
// Round 5: batched-z attention (batch*head in one dispatch), causal work
// skipping (upper-tile early-exit, triangular-K PV, causal softmax),
// 128x128 split-K=4 projections. Workspace tiered on ws_size (fallback =
// round-4's known-safe 110 MB layout).

typedef unsigned short bfu;                                  // raw bf16 bits
typedef short  s16x8 __attribute__((ext_vector_type(8)));    // 8 bf16 = 4 VGPR
typedef float  f32x4 __attribute__((ext_vector_type(4)));    // MFMA C/D frag

__device__ __forceinline__ bfu f2b(float f) {                // fp32 -> bf16 (RNE)
  unsigned int u = __float_as_uint(f);
  unsigned int r = (u + 0x7fffu + ((u >> 16) & 1u)) >> 16;
  return (bfu)r;
}
__device__ __forceinline__ float b2f(bfu h) {
  return __uint_as_float(((unsigned int)h) << 16);
}

// async global->LDS, 16 B per lane; LDS dest = wave-uniform base + lane*16
__device__ __forceinline__ void async16(const bfu* g, bfu* l) {
  __builtin_amdgcn_global_load_lds(
      (const __attribute__((address_space(1))) void*)g,
      (__attribute__((address_space(3))) void*)l, 16, 0, 0);
}

// ---------------------------------------------------------------------------
// GEMM: C[m,n] = sum_k A[m,k] * Bt[n,k]  (both K-contiguous), bf16 in, fp32 acc.
// Tile TM x TN = (WY*FI*16) x (WX*FJ*16), WY*WX waves, BK=32.
// global_load_lds dwordx4 staging, XOR column-group swizzle (bank-conflict
// free, verified R4: SQ_LDS_BANK_CONFLICT=0). XCD-cluster block swizzle (cx
// x-tiles per cluster). Two-level z (zo=z/zInner, zi=z%zInner) for batch,
// head, and split-K addressing. CAUSAL: scale+mask epilogue AND early-exit
// for tiles fully above the diagonal. TRIK: K clamped to tM+TM (P cols above
// the row-tile are exact zeros / never read). BIAS: 0 none, 1 col, 2 row.
// ---------------------------------------------------------------------------
template<int TM, int TN, int WY, int WX, int FI, int FJ,
         bool OUT_BF16, bool RELU, bool CAUSAL, int BIAS, bool TRIK>
__global__ __launch_bounds__(WY * WX * 64)
void gemm_bt(const bfu* __restrict__ A, long lda, long sAo, long sAi,
             const bfu* __restrict__ B, long ldb, long sBo, long sBi,
             void* __restrict__ Cv, long ldc, long sCo, long sCi,
             const float* __restrict__ bias,
             int K, int zInner, float scale, int cx)
{
  static_assert(TM == WY * FI * 16 && TN == WX * FJ * 16, "tile mismatch");
  constexpr int BK = 32;
  constexpr int NW = WY * WX;
  constexpr int AI = TM / (16 * NW);              // A staging instrs/wave
  constexpr int BI = TN / (16 * NW);              // B staging instrs/wave

  __shared__ __align__(16) bfu As[TM * BK];
  __shared__ __align__(16) bfu Bs[TN * BK];

  // ---- XCD-cluster tile decode (total%8==0, cx|NX, cx|perX, (NX/cx)|8) ----
  const int NX = gridDim.x, NY = gridDim.y;
  const int flat  = blockIdx.x + NX * (blockIdx.y + NY * blockIdx.z);
  const int total = NX * NY * gridDim.z;
  const int xcd = flat & 7, idx = flat >> 3;
  const int perX = total >> 3;
  const int clX  = NX / cx;
  const int ry   = perX / cx;
  const int tx   = (xcd % clX) * cx + idx % cx;
  const int yz   = (xcd / clX) * ry + idx / cx;
  const int ty   = yz % NY, tz = yz / NY;

  const int tM = ty * TM;
  const int tN = tx * TN;
  if (CAUSAL && tN >= tM + TM) return;            // fully-masked tile

  const int zo = tz / zInner, zi = tz - zo * zInner;
  A += (long)zo * sAo + (long)zi * sAi;
  B += (long)zo * sBo + (long)zi * sBi;
  const long cBase = (long)zo * sCo + (long)zi * sCi;

  const int t = threadIdx.x;
  const int wave = t >> 6, lane = t & 63;
  const int wr = wave / WX, wc = wave % WX;
  const int q = lane >> 4, l16 = lane & 15;

  // ---- staging addresses (lane -> row lane/4, col-group (lane&3)^swz(row)) ----
  const bfu* aG[AI]; bfu* aL[AI];
  const bfu* bG[BI]; bfu* bL[BI];
#pragma unroll
  for (int i2 = 0; i2 < AI; i2++) {
    const int rb = (i2 * NW + wave) * 16;
    const int r  = rb + (lane >> 2);
    const int g  = (lane & 3) ^ ((r >> 1) & 3);
    aG[i2] = A + (long)(tM + r) * lda + g * 8;
    aL[i2] = &As[rb * BK];
  }
#pragma unroll
  for (int i2 = 0; i2 < BI; i2++) {
    const int rb = (i2 * NW + wave) * 16;
    const int r  = rb + (lane >> 2);
    const int g  = (lane & 3) ^ ((r >> 1) & 3);
    bG[i2] = B + (long)(tN + r) * ldb + g * 8;
    bL[i2] = &Bs[rb * BK];
  }

  // ---- fragment LDS offsets (swizzled; k-invariant) ----
  int aOff[FI], bOff[FJ];
#pragma unroll
  for (int i = 0; i < FI; i++) {
    const int r = wr * FI * 16 + i * 16 + l16;
    aOff[i] = r * BK + ((q ^ ((r >> 1) & 3)) * 8);
  }
#pragma unroll
  for (int j = 0; j < FJ; j++) {
    const int r = wc * FJ * 16 + j * 16 + l16;
    bOff[j] = r * BK + ((q ^ ((r >> 1) & 3)) * 8);
  }

  const int Kend = TRIK ? ((tM + TM < K) ? tM + TM : K) : K;

  f32x4 acc[FI][FJ] = {};

  for (int k0 = 0; k0 < Kend; k0 += BK) {
    __syncthreads();
#pragma unroll
    for (int i2 = 0; i2 < AI; i2++) async16(aG[i2] + k0, aL[i2]);
#pragma unroll
    for (int i2 = 0; i2 < BI; i2++) async16(bG[i2] + k0, bL[i2]);
    __syncthreads();

    s16x8 af[FI], bfr[FJ];
#pragma unroll
    for (int i = 0; i < FI; i++) af[i]  = *(const s16x8*)&As[aOff[i]];
#pragma unroll
    for (int j = 0; j < FJ; j++) bfr[j] = *(const s16x8*)&Bs[bOff[j]];
#pragma unroll
    for (int i = 0; i < FI; i++)
#pragma unroll
      for (int j = 0; j < FJ; j++)
        acc[i][j] = __builtin_amdgcn_mfma_f32_16x16x32_bf16(af[i], bfr[j], acc[i][j], 0, 0, 0);
  }

  // Epilogue. C/D layout (m89/m91): col = lane&15, row = (lane>>4)*4 + reg.
  float* Cf = (float*)Cv;
  bfu*   Cb = (bfu*)Cv;
#pragma unroll
  for (int i = 0; i < FI; i++) {
    const int row0 = tM + wr * FI * 16 + i * 16 + q * 4;
#pragma unroll
    for (int j = 0; j < FJ; j++) {
      const int col = tN + wc * FJ * 16 + j * 16 + l16;
      float cbv = 0.0f;
      if (BIAS == 1) cbv = bias[col];
#pragma unroll
      for (int r = 0; r < 4; r++) {
        float v = acc[i][j][r];
        if (CAUSAL) { v *= scale; if (col > row0 + r) v = -1e30f; }
        if (BIAS == 1) v += cbv;
        if (BIAS == 2) v += bias[row0 + r];
        if (RELU) v = fmaxf(v, 0.0f);
        long idxc = cBase + (long)(row0 + r) * ldc + col;
        if (OUT_BF16) Cb[idxc] = f2b(v); else Cf[idxc] = v;
      }
    }
  }
}

// ---------------------------------------------------------------------------
// fp32 [R,C] -> bf16 [C,R] transpose+convert (used for W_out)
// ---------------------------------------------------------------------------
__global__ void transpose_cvt(const float* __restrict__ src, bfu* __restrict__ dst,
                              int R, int C)
{
  __shared__ bfu tile[64 * 65];
  const int t = threadIdx.x;
  const int tc = blockIdx.x * 64, tr = blockIdx.y * 64;
#pragma unroll
  for (int i = 0; i < 16; i++) {
    int idx = t + i * 256; int r = idx >> 6, c = idx & 63;
    tile[r * 65 + c] = f2b(src[(long)(tr + r) * C + tc + c]);
  }
  __syncthreads();
#pragma unroll
  for (int i = 0; i < 16; i++) {
    int idx = t + i * 256; int r = idx >> 6, c = idx & 63;
    dst[(long)(tc + r) * R + tr + c] = tile[c * 65 + r];
  }
}

// ---------------------------------------------------------------------------
// Fused per-layer weight prep (transposes + q|k bias pack). 2592 blocks.
// ---------------------------------------------------------------------------
__global__ void prep_layer(const float* __restrict__ Wq, const float* __restrict__ Wk,
                           const float* __restrict__ Wv, const float* __restrict__ Wo,
                           const float* __restrict__ W1, const float* __restrict__ W2,
                           const float* __restrict__ bq, const float* __restrict__ bk,
                           bfu* __restrict__ qkvwT, bfu* __restrict__ woT,
                           bfu* __restrict__ w1T, bfu* __restrict__ w2T,
                           float* __restrict__ qkb)
{
  const int bid = blockIdx.x;
  const int t = threadIdx.x;

  if (bid >= 2560) {                        // bias pack: 8192 elems, 32 blocks
    int j = (bid - 2560) * 256 + t;
    qkb[j] = (j < 4096) ? bq[j] : bk[j - 4096];
    return;
  }

  const float* src; bfu* dst; int R, C, ctiles, local;
  if (bid < 512)       { src = Wq; dst = qkvwT;              R = 512;  C = 4096; ctiles = 64; local = bid; }
  else if (bid < 1024) { src = Wk; dst = qkvwT + 4096L*512;  R = 512;  C = 4096; ctiles = 64; local = bid - 512; }
  else if (bid < 1536) { src = Wv; dst = qkvwT + 8192L*512;  R = 512;  C = 4096; ctiles = 64; local = bid - 1024; }
  else if (bid < 2048) { src = Wo; dst = woT;                R = 4096; C = 512;  ctiles = 8;  local = bid - 1536; }
  else if (bid < 2304) { src = W1; dst = w1T;                R = 512;  C = 2048; ctiles = 32; local = bid - 2048; }
  else                 { src = W2; dst = w2T;                R = 2048; C = 512;  ctiles = 8;  local = bid - 2304; }
  const int tc = (local % ctiles) * 64;
  const int tr = (local / ctiles) * 64;

  __shared__ bfu tile[64 * 65];
#pragma unroll
  for (int i = 0; i < 16; i++) {
    int idx = t + i * 256; int r = idx >> 6, c = idx & 63;
    tile[r * 65 + c] = f2b(src[(long)(tr + r) * C + tc + c]);
  }
  __syncthreads();
#pragma unroll
  for (int i = 0; i < 16; i++) {
    int idx = t + i * 256; int r = idx >> 6, c = idx & 63;
    dst[(long)(tc + r) * R + tr + c] = tile[c * 65 + r];
  }
}

// block (256 threads) stats over 512 values (2/thread pre-summed by caller)
__device__ __forceinline__ void blk_stats(float s, float ss, float* red,
                                          float& mean, float& var)
{
#pragma unroll
  for (int off = 32; off; off >>= 1) { s += __shfl_down(s, off); ss += __shfl_down(ss, off); }
  int w = threadIdx.x >> 6;
  if ((threadIdx.x & 63) == 0) { red[w] = s; red[4 + w] = ss; }
  __syncthreads();
  s  = red[0] + red[1] + red[2] + red[3];
  ss = red[4] + red[5] + red[6] + red[7];
  mean = s * (1.0f / 512.0f);
  var  = ss * (1.0f / 512.0f) - mean * mean;
}

__global__ void embed_ln(const int* __restrict__ ids, const float* __restrict__ tok,
                         const float* __restrict__ pos, const float* __restrict__ g,
                         const float* __restrict__ bta, float* __restrict__ h,
                         bfu* __restrict__ hb)
{
  __shared__ float red[8];
  const int row = blockIdx.x;          // b*S + s
  const int s = row & 1023;
  const int t = threadIdx.x;
  const long base = (long)row * 512;
  const int id = ids[row];
  float x0 = tok[(long)id * 512 + t]       + pos[(long)s * 512 + t];
  float x1 = tok[(long)id * 512 + t + 256] + pos[(long)s * 512 + t + 256];
  float mean, var;
  blk_stats(x0 + x1, x0 * x0 + x1 * x1, red, mean, var);
  float rstd = rsqrtf(var + 1e-5f);
  float y0 = (x0 - mean) * rstd * g[t]       + bta[t];
  float y1 = (x1 - mean) * rstd * g[t + 256] + bta[t + 256];
  h[base + t] = y0;        h[base + t + 256] = y1;
  hb[base + t] = f2b(y0);  hb[base + t + 256] = f2b(y1);
}

// x = sum_{s<n} p[i+s*ps] + bias[col] + h[i] -> LN -> h, hb
__global__ void add_ln_redN(const float* __restrict__ p, long ps, int n,
                            const float* __restrict__ bias,
                            float* __restrict__ h, bfu* __restrict__ hb,
                            const float* __restrict__ g, const float* __restrict__ bta)
{
  __shared__ float red[8];
  const long base = (long)blockIdx.x * 512;
  const int t = threadIdx.x;
  float x0 = bias[t]       + h[base + t];
  float x1 = bias[t + 256] + h[base + t + 256];
  for (int s = 0; s < n; s++) {
    x0 += p[base + (long)s * ps + t];
    x1 += p[base + (long)s * ps + t + 256];
  }
  float mean, var;
  blk_stats(x0 + x1, x0 * x0 + x1 * x1, red, mean, var);
  float rstd = rsqrtf(var + 1e-5f);
  float y0 = (x0 - mean) * rstd * g[t]       + bta[t];
  float y1 = (x1 - mean) * rstd * g[t + 256] + bta[t + 256];
  h[base + t] = y0;        h[base + t + 256] = y1;
  hb[base + t] = f2b(y0);  hb[base + t + 256] = f2b(y1);
}

// out[i] = sum_{s<n} p[i+s*ps] + bias[col]
__global__ void out_redN(const float* __restrict__ p, long ps, int n,
                         const float* __restrict__ bias, float* __restrict__ out)
{
  const long base = (long)blockIdx.x * 512;
  const int t = threadIdx.x;
  float x0 = bias[t], x1 = bias[t + 256];
  for (int s = 0; s < n; s++) {
    x0 += p[base + (long)s * ps + t];
    x1 += p[base + (long)s * ps + t + 256];
  }
  out[base + t] = x0;
  out[base + t + 256] = x1;
}

// Causal in-place softmax, row r = blockIdx.x & 1023 of a 1024-wide bf16 row.
// Reads cols <= r only; writes cols < roundup128(r+1) (PV never reads beyond).
__global__ void softmax_causal(bfu* __restrict__ P)
{
  __shared__ float red[8];
  const long base = (long)blockIdx.x * 1024;
  const int r = blockIdx.x & 1023;
  const int wlim = ((r >> 7) + 1) << 7;
  const int t = threadIdx.x;
  float v[4];
  float mx = -3e30f;
#pragma unroll
  for (int i = 0; i < 4; i++) {
    const int col = t + i * 256;
    v[i] = (col <= r) ? b2f(P[base + col]) : -3e30f;
    mx = fmaxf(mx, v[i]);
  }
#pragma unroll
  for (int off = 32; off; off >>= 1) mx = fmaxf(mx, __shfl_xor(mx, off));
  int w = t >> 6;
  if ((t & 63) == 0) red[w] = mx;
  __syncthreads();
  mx = fmaxf(fmaxf(red[0], red[1]), fmaxf(red[2], red[3]));
  float e[4], sum = 0.0f;
#pragma unroll
  for (int i = 0; i < 4; i++) {
    const int col = t + i * 256;
    e[i] = (col <= r) ? expf(v[i] - mx) : 0.0f;
    sum += e[i];
  }
#pragma unroll
  for (int off = 32; off; off >>= 1) sum += __shfl_xor(sum, off);
  __syncthreads();
  if ((t & 63) == 0) red[4 + w] = sum;
  __syncthreads();
  sum = red[4] + red[5] + red[6] + red[7];
  float inv = 1.0f / sum;
#pragma unroll
  for (int i = 0; i < 4; i++) {
    const int col = t + i * 256;
    if (col < wlim) P[base + col] = f2b(e[i] * inv);
  }
}

// ---------------------------------------------------------------------------
extern "C" void kernel_launch(void* const* d_in, const int* in_sizes, int n_in,
                              void* d_out, int out_size, void* d_ws, size_t ws_size,
                              hipStream_t stream)
{
  const int*   x     = (const int*)  d_in[0];
  const float* tok   = (const float*)d_in[1];
  const float* pos   = (const float*)d_in[2];
  const float* lnig  = (const float*)d_in[3];
  const float* lnib  = (const float*)d_in[4];
  const float* Wq    = (const float*)d_in[5];
  const float* bq    = (const float*)d_in[6];
  const float* Wk    = (const float*)d_in[7];
  const float* bk    = (const float*)d_in[8];
  const float* Wv    = (const float*)d_in[9];
  const float* bv    = (const float*)d_in[10];
  const float* Wo    = (const float*)d_in[11];
  const float* bo    = (const float*)d_in[12];
  const float* ln1g  = (const float*)d_in[13];
  const float* ln1b  = (const float*)d_in[14];
  const float* W1    = (const float*)d_in[15];
  const float* b1    = (const float*)d_in[16];
  const float* W2    = (const float*)d_in[17];
  const float* b2    = (const float*)d_in[18];
  const float* ln2g  = (const float*)d_in[19];
  const float* ln2b  = (const float*)d_in[20];
  const float* Wout  = (const float*)d_in[21];
  const float* bout  = (const float*)d_in[22];

  // ---- workspace tiering (deterministic in ws_size) ----
  const size_t MB = 1024 * 1024;
  int gb; bool s4;                           // batches per attention group; split-K=4 path
  if      (ws_size >= 236 * MB) { gb = 4; s4 = true;  }
  else if (ws_size >= 169 * MB) { gb = 2; s4 = true;  }
  else if (ws_size >= 152 * MB) { gb = 1; s4 = true;  }
  else                          { gb = 1; s4 = false; }   // == round-4 layout (~110 MB)

  const size_t qkBytes = (size_t)gb * 1024 * 8192 * 2;
  const size_t scB0    = (size_t)gb * 8 * 1024 * 1024 * 2;
  const size_t scBytes = s4 ? (scB0 > 33554432 ? scB0 : 33554432) : 16777216;
  const size_t vtB0    = (size_t)gb * 8 * 512 * 1024 * 2;
  const size_t vtBytes = s4 ? (vtB0 > 33554432 ? vtB0 : 33554432) : 8388608;

  char* wsp = (char*)d_ws;
  auto alloc = [&](size_t bytes) { char* p = wsp; wsp += (bytes + 255) & ~(size_t)255; return p; };

  bfu*   qkvwT = (bfu*)  alloc(12288L * 512 * 2);
  bfu*   woT   = (bfu*)  alloc(512L * 4096 * 2);
  bfu*   w1T   = (bfu*)  alloc(2048L * 512 * 2);
  bfu*   w2T   = (bfu*)  alloc(512L * 2048 * 2);
  bfu*   woutT = (bfu*)  alloc(512L * 512 * 2);
  float* qkb   = (float*)alloc(8192L * 4);
  float* h     = (float*)alloc(4096L * 512 * 4);        // fp32 residual stream
  bfu*   hb    = (bfu*)  alloc(4096L * 512 * 2);        // bf16 copy (GEMM A operand)
  bfu*   attn  = (bfu*)  alloc(4096L * 4096 * 2);       // attention out, all tokens
  bfu*   qkS   = (bfu*)  alloc(qkBytes);                // q|k group; (D) FFN2/final partials
  bfu*   scS   = (bfu*)  alloc(scBytes);                // scores; Wo partials; FFN hidden
  bfu*   vTS   = (bfu*)  alloc(vtBytes);                // v^T group; (s4) FFN2/final partials

  float* pWo = (float*)scS;
  float* pF  = s4 ? (float*)vTS : (float*)qkS;
  const int nspl = s4 ? 4 : 2;

  embed_ln<<<4096, 256, 0, stream>>>(x, tok, pos, lnig, lnib, h, hb);
  transpose_cvt<<<dim3(8, 8), 256, 0, stream>>>(Wout, woutT, 512, 512);

  const float invsq = 0.044194173824159216f;  // 1/sqrt(512)
  const long  PSTR  = 4096L * 512;            // split-K partial stride (floats)

  for (int l = 0; l < 6; l++) {
    prep_layer<<<2592, 256, 0, stream>>>(
        Wq + (long)l*512*4096, Wk + (long)l*512*4096, Wv + (long)l*512*4096,
        Wo + (long)l*4096*512, W1 + (long)l*512*2048, W2 + (long)l*2048*512,
        bq + (long)l*4096, bk + (long)l*4096,
        qkvwT, woT, w1T, w2T, qkb);

    for (int g0 = 0; g0 < 4; g0 += gb) {
      const bfu* hbG = hb + (long)g0 * 1024 * 512;

      // q|k: [gb*1024,512] x [8192,512]^T -> qkS (+col bias)
      gemm_bt<128,128,2,2,4,4,true,false,false,1,false>
          <<<dim3(64, gb*8, 1), 256, 0, stream>>>(
          hbG, 512, 0, 0, qkvwT, 512, 0, 0, qkS, 8192, 0, 0,
          qkb, 512, 1, 1.0f, 8);

      // vT[b][h][d][s] = Wv^T @ h_b^T (+row bias): z = batch
      gemm_bt<128,128,2,2,4,4,true,false,false,2,false>
          <<<dim3(8, 32, gb), 256, 0, stream>>>(
          qkvwT + 8192L*512, 512, 0, 0,
          hbG, 512, 0, 1024L*512,
          vTS, 1024, 0, 4096L*1024,
          bv + (long)l*4096, 512, gb, 1.0f, 8);

      // scores = (q k^T)/sqrt(dh), causal (upper tiles skipped): z = b*8+h
      gemm_bt<128,128,2,2,4,4,true,false,true,0,false>
          <<<dim3(8, 8, gb*8), 256, 0, stream>>>(
          qkS,        8192, 1024L*8192, 512,
          qkS + 4096, 8192, 1024L*8192, 512,
          scS, 1024, 8L*1024*1024, 1024L*1024,
          nullptr, 512, 8, invsq, 8);

      softmax_causal<<<gb*8192, 256, 0, stream>>>(scS);

      // attn = P @ v, triangular K: z = b*8+h
      gemm_bt<128,64,2,2,4,2,true,false,false,0,true>
          <<<dim3(8, 8, gb*8), 256, 0, stream>>>(
          scS, 1024, 8L*1024*1024, 1024L*1024,
          vTS, 1024, 8L*512*1024,  512L*1024,
          attn + (long)g0*1024*4096, 4096, 1024L*4096, 512,
          nullptr, 1024, 8, 1.0f, 8);
    }

    // Wo projection -> fp32 partials
    if (s4) {
      gemm_bt<128,128,2,2,4,4,false,false,false,0,false>
          <<<dim3(4, 32, 4), 256, 0, stream>>>(
          attn, 4096, 0, 1024, woT, 4096, 0, 1024,
          pWo, 512, 0, PSTR, nullptr, 1024, 4, 1.0f, 4);
    } else {
      gemm_bt<128,64,2,2,4,2,false,false,false,0,false>
          <<<dim3(8, 32, 2), 256, 0, stream>>>(
          attn, 4096, 0, 2048, woT, 4096, 0, 2048,
          pWo, 512, 0, PSTR, nullptr, 2048, 1, 1.0f, 8);
    }
    add_ln_redN<<<4096, 256, 0, stream>>>(pWo, PSTR, nspl, bo + (long)l*512,
                                          h, hb, ln1g + (long)l*512, ln1b + (long)l*512);

    // FFN1 (+ReLU) -> bf16 hidden in scS [4096,2048]
    gemm_bt<128,128,2,2,4,4,true,true,false,1,false>
        <<<dim3(16, 32, 1), 256, 0, stream>>>(
        hb, 512, 0, 0, w1T, 512, 0, 0, scS, 2048, 0, 0,
        b1 + (long)l*2048, 512, 1, 1.0f, 16);

    // FFN2 -> fp32 partials
    if (s4) {
      gemm_bt<128,128,2,2,4,4,false,false,false,0,false>
          <<<dim3(4, 32, 4), 256, 0, stream>>>(
          scS, 2048, 0, 512, w2T, 2048, 0, 512,
          pF, 512, 0, PSTR, nullptr, 512, 4, 1.0f, 4);
    } else {
      gemm_bt<128,64,2,2,4,2,false,false,false,0,false>
          <<<dim3(8, 32, 2), 256, 0, stream>>>(
          scS, 2048, 0, 1024, w2T, 2048, 0, 1024,
          pF, 512, 0, PSTR, nullptr, 1024, 1, 1.0f, 8);
    }
    add_ln_redN<<<4096, 256, 0, stream>>>(pF, PSTR, nspl, b2 + (long)l*512,
                                          h, hb, ln2g + (long)l*512, ln2b + (long)l*512);
  }

  // final projection
  if (s4) {
    gemm_bt<128,128,2,2,4,4,false,false,false,0,false>
        <<<dim3(4, 32, 4), 256, 0, stream>>>(
        hb, 512, 0, 128, woutT, 512, 0, 128,
        pF, 512, 0, PSTR, nullptr, 128, 4, 1.0f, 4);
  } else {
    gemm_bt<128,64,2,2,4,2,false,false,false,0,false>
        <<<dim3(8, 32, 2), 256, 0, stream>>>(
        hb, 512, 0, 256, woutT, 512, 0, 256,
        pF, 512, 0, PSTR, nullptr, 256, 1, 1.0f, 8);
  }
  out_redN<<<4096, 256, 0, stream>>>(pF, PSTR, nspl, bout, (float*)d_out);
}

// Round 6
// 1920.378 us; speedup vs baseline: 1.7910x; 1.0633x over previous
//
#include <hip/hip_runtime.h>
#include <math.h>

// AutoregressiveTransformer on MI355X (gfx950).
// Round 6: BK=64 K-loop (two proven BK=32 LDS panels per barrier) -> half the
// vmcnt(0) barrier drains per GEMM. Everything else = round 5 (batched-z
// attention, causal skipping, split-K projections, tiered workspace).

typedef unsigned short bfu;                                  // raw bf16 bits
typedef short  s16x8 __attribute__((ext_vector_type(8)));    // 8 bf16 = 4 VGPR
typedef float  f32x4 __attribute__((ext_vector_type(4)));    // MFMA C/D frag

__device__ __forceinline__ bfu f2b(float f) {                // fp32 -> bf16 (RNE)
  unsigned int u = __float_as_uint(f);
  unsigned int r = (u + 0x7fffu + ((u >> 16) & 1u)) >> 16;
  return (bfu)r;
}
__device__ __forceinline__ float b2f(bfu h) {
  return __uint_as_float(((unsigned int)h) << 16);
}

// async global->LDS, 16 B per lane; LDS dest = wave-uniform base + lane*16
__device__ __forceinline__ void async16(const bfu* g, bfu* l) {
  __builtin_amdgcn_global_load_lds(
      (const __attribute__((address_space(1))) void*)g,
      (__attribute__((address_space(3))) void*)l, 16, 0, 0);
}

// ---------------------------------------------------------------------------
// GEMM: C[m,n] = sum_k A[m,k] * Bt[n,k]  (both K-contiguous), bf16 in, fp32 acc.
// Tile TM x TN = (WY*FI*16) x (WX*FJ*16), WY*WX waves.
// K-loop: BK=64 per barrier, stored as TWO BK=32 LDS panels using the R4-proven
// XOR column-group swizzle (SQ_LDS_BANK_CONFLICT=0) -> 2x MFMA per drain.
// XCD-cluster block swizzle (cx x-tiles/cluster). Two-level z (zo=z/zInner,
// zi=z%zInner) for batch/head/split-K. CAUSAL: scale+mask epilogue + early-exit
// above diagonal. TRIK: K clamped to tM+TM. BIAS: 0 none, 1 col, 2 row.
// Requires K % 64 == 0 (all call sites satisfy).
// ---------------------------------------------------------------------------
template<int TM, int TN, int WY, int WX, int FI, int FJ,
         bool OUT_BF16, bool RELU, bool CAUSAL, int BIAS, bool TRIK>
__global__ __launch_bounds__(WY * WX * 64)
void gemm_bt(const bfu* __restrict__ A, long lda, long sAo, long sAi,
             const bfu* __restrict__ B, long ldb, long sBo, long sBi,
             void* __restrict__ Cv, long ldc, long sCo, long sCi,
             const float* __restrict__ bias,
             int K, int zInner, float scale, int cx)
{
  static_assert(TM == WY * FI * 16 && TN == WX * FJ * 16, "tile mismatch");
  constexpr int NW = WY * WX;
  constexpr int AI = TM / (16 * NW);              // A staging instrs/wave/panel
  constexpr int BI = TN / (16 * NW);              // B staging instrs/wave/panel
  constexpr int APAN = TM * 32;                   // panel stride (elements)
  constexpr int BPAN = TN * 32;

  __shared__ __align__(16) bfu As[2 * APAN];
  __shared__ __align__(16) bfu Bs[2 * BPAN];

  // ---- XCD-cluster tile decode (total%8==0, cx|NX, cx|perX) ----
  const int NX = gridDim.x, NY = gridDim.y;
  const int flat  = blockIdx.x + NX * (blockIdx.y + NY * blockIdx.z);
  const int total = NX * NY * gridDim.z;
  const int xcd = flat & 7, idx = flat >> 3;
  const int perX = total >> 3;
  const int clX  = NX / cx;
  const int ry   = perX / cx;
  const int tx   = (xcd % clX) * cx + idx % cx;
  const int yz   = (xcd / clX) * ry + idx / cx;
  const int ty   = yz % NY, tz = yz / NY;

  const int tM = ty * TM;
  const int tN = tx * TN;
  if (CAUSAL && tN >= tM + TM) return;            // fully-masked tile

  const int zo = tz / zInner, zi = tz - zo * zInner;
  A += (long)zo * sAo + (long)zi * sAi;
  B += (long)zo * sBo + (long)zi * sBi;
  const long cBase = (long)zo * sCo + (long)zi * sCi;

  const int t = threadIdx.x;
  const int wave = t >> 6, lane = t & 63;
  const int wr = wave / WX, wc = wave % WX;
  const int q = lane >> 4, l16 = lane & 15;

  // ---- staging addresses (lane -> row lane/4, col-group (lane&3)^swz(row)) ----
  const bfu* aG[AI]; bfu* aL[AI];
  const bfu* bG[BI]; bfu* bL[BI];
#pragma unroll
  for (int i2 = 0; i2 < AI; i2++) {
    const int rb = (i2 * NW + wave) * 16;
    const int r  = rb + (lane >> 2);
    const int g  = (lane & 3) ^ ((r >> 1) & 3);
    aG[i2] = A + (long)(tM + r) * lda + g * 8;
    aL[i2] = &As[rb * 32];
  }
#pragma unroll
  for (int i2 = 0; i2 < BI; i2++) {
    const int rb = (i2 * NW + wave) * 16;
    const int r  = rb + (lane >> 2);
    const int g  = (lane & 3) ^ ((r >> 1) & 3);
    bG[i2] = B + (long)(tN + r) * ldb + g * 8;
    bL[i2] = &Bs[rb * 32];
  }

  // ---- fragment LDS offsets (swizzled; k-invariant, per panel) ----
  int aOff[FI], bOff[FJ];
#pragma unroll
  for (int i = 0; i < FI; i++) {
    const int r = wr * FI * 16 + i * 16 + l16;
    aOff[i] = r * 32 + ((q ^ ((r >> 1) & 3)) * 8);
  }
#pragma unroll
  for (int j = 0; j < FJ; j++) {
    const int r = wc * FJ * 16 + j * 16 + l16;
    bOff[j] = r * 32 + ((q ^ ((r >> 1) & 3)) * 8);
  }

  const int Kend = TRIK ? ((tM + TM < K) ? tM + TM : K) : K;

  f32x4 acc[FI][FJ] = {};

  for (int k0 = 0; k0 < Kend; k0 += 64) {
    __syncthreads();
#pragma unroll
    for (int m = 0; m < 2; m++) {
#pragma unroll
      for (int i2 = 0; i2 < AI; i2++) async16(aG[i2] + k0 + m * 32, aL[i2] + m * APAN);
#pragma unroll
      for (int i2 = 0; i2 < BI; i2++) async16(bG[i2] + k0 + m * 32, bL[i2] + m * BPAN);
    }
    __syncthreads();

#pragma unroll
    for (int m = 0; m < 2; m++) {
      s16x8 af[FI], bfr[FJ];
#pragma unroll
      for (int i = 0; i < FI; i++) af[i]  = *(const s16x8*)&As[m * APAN + aOff[i]];
#pragma unroll
      for (int j = 0; j < FJ; j++) bfr[j] = *(const s16x8*)&Bs[m * BPAN + bOff[j]];
#pragma unroll
      for (int i = 0; i < FI; i++)
#pragma unroll
        for (int j = 0; j < FJ; j++)
          acc[i][j] = __builtin_amdgcn_mfma_f32_16x16x32_bf16(af[i], bfr[j], acc[i][j], 0, 0, 0);
    }
  }

  // Epilogue. C/D layout (m89/m91): col = lane&15, row = (lane>>4)*4 + reg.
  float* Cf = (float*)Cv;
  bfu*   Cb = (bfu*)Cv;
#pragma unroll
  for (int i = 0; i < FI; i++) {
    const int row0 = tM + wr * FI * 16 + i * 16 + q * 4;
#pragma unroll
    for (int j = 0; j < FJ; j++) {
      const int col = tN + wc * FJ * 16 + j * 16 + l16;
      float cbv = 0.0f;
      if (BIAS == 1) cbv = bias[col];
#pragma unroll
      for (int r = 0; r < 4; r++) {
        float v = acc[i][j][r];
        if (CAUSAL) { v *= scale; if (col > row0 + r) v = -1e30f; }
        if (BIAS == 1) v += cbv;
        if (BIAS == 2) v += bias[row0 + r];
        if (RELU) v = fmaxf(v, 0.0f);
        long idxc = cBase + (long)(row0 + r) * ldc + col;
        if (OUT_BF16) Cb[idxc] = f2b(v); else Cf[idxc] = v;
      }
    }
  }
}

// ---------------------------------------------------------------------------
// fp32 [R,C] -> bf16 [C,R] transpose+convert (used for W_out)
// ---------------------------------------------------------------------------
__global__ void transpose_cvt(const float* __restrict__ src, bfu* __restrict__ dst,
                              int R, int C)
{
  __shared__ bfu tile[64 * 65];
  const int t = threadIdx.x;
  const int tc = blockIdx.x * 64, tr = blockIdx.y * 64;
#pragma unroll
  for (int i = 0; i < 16; i++) {
    int idx = t + i * 256; int r = idx >> 6, c = idx & 63;
    tile[r * 65 + c] = f2b(src[(long)(tr + r) * C + tc + c]);
  }
  __syncthreads();
#pragma unroll
  for (int i = 0; i < 16; i++) {
    int idx = t + i * 256; int r = idx >> 6, c = idx & 63;
    dst[(long)(tc + r) * R + tr + c] = tile[c * 65 + r];
  }
}

// ---------------------------------------------------------------------------
// Fused per-layer weight prep (transposes + q|k bias pack). 2592 blocks.
// ---------------------------------------------------------------------------
__global__ void prep_layer(const float* __restrict__ Wq, const float* __restrict__ Wk,
                           const float* __restrict__ Wv, const float* __restrict__ Wo,
                           const float* __restrict__ W1, const float* __restrict__ W2,
                           const float* __restrict__ bq, const float* __restrict__ bk,
                           bfu* __restrict__ qkvwT, bfu* __restrict__ woT,
                           bfu* __restrict__ w1T, bfu* __restrict__ w2T,
                           float* __restrict__ qkb)
{
  const int bid = blockIdx.x;
  const int t = threadIdx.x;

  if (bid >= 2560) {                        // bias pack: 8192 elems, 32 blocks
    int j = (bid - 2560) * 256 + t;
    qkb[j] = (j < 4096) ? bq[j] : bk[j - 4096];
    return;
  }

  const float* src; bfu* dst; int R, C, ctiles, local;
  if (bid < 512)       { src = Wq; dst = qkvwT;              R = 512;  C = 4096; ctiles = 64; local = bid; }
  else if (bid < 1024) { src = Wk; dst = qkvwT + 4096L*512;  R = 512;  C = 4096; ctiles = 64; local = bid - 512; }
  else if (bid < 1536) { src = Wv; dst = qkvwT + 8192L*512;  R = 512;  C = 4096; ctiles = 64; local = bid - 1024; }
  else if (bid < 2048) { src = Wo; dst = woT;                R = 4096; C = 512;  ctiles = 8;  local = bid - 1536; }
  else if (bid < 2304) { src = W1; dst = w1T;                R = 512;  C = 2048; ctiles = 32; local = bid - 2048; }
  else                 { src = W2; dst = w2T;                R = 2048; C = 512;  ctiles = 8;  local = bid - 2304; }
  const int tc = (local % ctiles) * 64;
  const int tr = (local / ctiles) * 64;

  __shared__ bfu tile[64 * 65];
#pragma unroll
  for (int i = 0; i < 16; i++) {
    int idx = t + i * 256; int r = idx >> 6, c = idx & 63;
    tile[r * 65 + c] = f2b(src[(long)(tr + r) * C + tc + c]);
  }
  __syncthreads();
#pragma unroll
  for (int i = 0; i < 16; i++) {
    int idx = t + i * 256; int r = idx >> 6, c = idx & 63;
    dst[(long)(tc + r) * R + tr + c] = tile[c * 65 + r];
  }
}

// block (256 threads) stats over 512 values (2/thread pre-summed by caller)
__device__ __forceinline__ void blk_stats(float s, float ss, float* red,
                                          float& mean, float& var)
{
#pragma unroll
  for (int off = 32; off; off >>= 1) { s += __shfl_down(s, off); ss += __shfl_down(ss, off); }
  int w = threadIdx.x >> 6;
  if ((threadIdx.x & 63) == 0) { red[w] = s; red[4 + w] = ss; }
  __syncthreads();
  s  = red[0] + red[1] + red[2] + red[3];
  ss = red[4] + red[5] + red[6] + red[7];
  mean = s * (1.0f / 512.0f);
  var  = ss * (1.0f / 512.0f) - mean * mean;
}

__global__ void embed_ln(const int* __restrict__ ids, const float* __restrict__ tok,
                         const float* __restrict__ pos, const float* __restrict__ g,
                         const float* __restrict__ bta, float* __restrict__ h,
                         bfu* __restrict__ hb)
{
  __shared__ float red[8];
  const int row = blockIdx.x;          // b*S + s
  const int s = row & 1023;
  const int t = threadIdx.x;
  const long base = (long)row * 512;
  const int id = ids[row];
  float x0 = tok[(long)id * 512 + t]       + pos[(long)s * 512 + t];
  float x1 = tok[(long)id * 512 + t + 256] + pos[(long)s * 512 + t + 256];
  float mean, var;
  blk_stats(x0 + x1, x0 * x0 + x1 * x1, red, mean, var);
  float rstd = rsqrtf(var + 1e-5f);
  float y0 = (x0 - mean) * rstd * g[t]       + bta[t];
  float y1 = (x1 - mean) * rstd * g[t + 256] + bta[t + 256];
  h[base + t] = y0;        h[base + t + 256] = y1;
  hb[base + t] = f2b(y0);  hb[base + t + 256] = f2b(y1);
}

// x = sum_{s<n} p[i+s*ps] + bias[col] + h[i] -> LN -> h, hb
__global__ void add_ln_redN(const float* __restrict__ p, long ps, int n,
                            const float* __restrict__ bias,
                            float* __restrict__ h, bfu* __restrict__ hb,
                            const float* __restrict__ g, const float* __restrict__ bta)
{
  __shared__ float red[8];
  const long base = (long)blockIdx.x * 512;
  const int t = threadIdx.x;
  float x0 = bias[t]       + h[base + t];
  float x1 = bias[t + 256] + h[base + t + 256];
  for (int s = 0; s < n; s++) {
    x0 += p[base + (long)s * ps + t];
    x1 += p[base + (long)s * ps + t + 256];
  }
  float mean, var;
  blk_stats(x0 + x1, x0 * x0 + x1 * x1, red, mean, var);
  float rstd = rsqrtf(var + 1e-5f);
  float y0 = (x0 - mean) * rstd * g[t]       + bta[t];
  float y1 = (x1 - mean) * rstd * g[t + 256] + bta[t + 256];
  h[base + t] = y0;        h[base + t + 256] = y1;
  hb[base + t] = f2b(y0);  hb[base + t + 256] = f2b(y1);
}

// out[i] = sum_{s<n} p[i+s*ps] + bias[col]
__global__ void out_redN(const float* __restrict__ p, long ps, int n,
                         const float* __restrict__ bias, float* __restrict__ out)
{
  const long base = (long)blockIdx.x * 512;
  const int t = threadIdx.x;
  float x0 = bias[t], x1 = bias[t + 256];
  for (int s = 0; s < n; s++) {
    x0 += p[base + (long)s * ps + t];
    x1 += p[base + (long)s * ps + t + 256];
  }
  out[base + t] = x0;
  out[base + t + 256] = x1;
}

// Causal in-place softmax, row r = blockIdx.x & 1023 of a 1024-wide bf16 row.
// Reads cols <= r only; writes cols < roundup128(r+1) (PV never reads beyond).
__global__ void softmax_causal(bfu* __restrict__ P)
{
  __shared__ float red[8];
  const long base = (long)blockIdx.x * 1024;
  const int r = blockIdx.x & 1023;
  const int wlim = ((r >> 7) + 1) << 7;
  const int t = threadIdx.x;
  float v[4];
  float mx = -3e30f;
#pragma unroll
  for (int i = 0; i < 4; i++) {
    const int col = t + i * 256;
    v[i] = (col <= r) ? b2f(P[base + col]) : -3e30f;
    mx = fmaxf(mx, v[i]);
  }
#pragma unroll
  for (int off = 32; off; off >>= 1) mx = fmaxf(mx, __shfl_xor(mx, off));
  int w = t >> 6;
  if ((t & 63) == 0) red[w] = mx;
  __syncthreads();
  mx = fmaxf(fmaxf(red[0], red[1]), fmaxf(red[2], red[3]));
  float e[4], sum = 0.0f;
#pragma unroll
  for (int i = 0; i < 4; i++) {
    const int col = t + i * 256;
    e[i] = (col <= r) ? expf(v[i] - mx) : 0.0f;
    sum += e[i];
  }
#pragma unroll
  for (int off = 32; off; off >>= 1) sum += __shfl_xor(sum, off);
  __syncthreads();
  if ((t & 63) == 0) red[4 + w] = sum;
  __syncthreads();
  sum = red[4] + red[5] + red[6] + red[7];
  float inv = 1.0f / sum;
#pragma unroll
  for (int i = 0; i < 4; i++) {
    const int col = t + i * 256;
    if (col < wlim) P[base + col] = f2b(e[i] * inv);
  }
}

// ---------------------------------------------------------------------------
extern "C" void kernel_launch(void* const* d_in, const int* in_sizes, int n_in,
                              void* d_out, int out_size, void* d_ws, size_t ws_size,
                              hipStream_t stream)
{
  const int*   x     = (const int*)  d_in[0];
  const float* tok   = (const float*)d_in[1];
  const float* pos   = (const float*)d_in[2];
  const float* lnig  = (const float*)d_in[3];
  const float* lnib  = (const float*)d_in[4];
  const float* Wq    = (const float*)d_in[5];
  const float* bq    = (const float*)d_in[6];
  const float* Wk    = (const float*)d_in[7];
  const float* bk    = (const float*)d_in[8];
  const float* Wv    = (const float*)d_in[9];
  const float* bv    = (const float*)d_in[10];
  const float* Wo    = (const float*)d_in[11];
  const float* bo    = (const float*)d_in[12];
  const float* ln1g  = (const float*)d_in[13];
  const float* ln1b  = (const float*)d_in[14];
  const float* W1    = (const float*)d_in[15];
  const float* b1    = (const float*)d_in[16];
  const float* W2    = (const float*)d_in[17];
  const float* b2    = (const float*)d_in[18];
  const float* ln2g  = (const float*)d_in[19];
  const float* ln2b  = (const float*)d_in[20];
  const float* Wout  = (const float*)d_in[21];
  const float* bout  = (const float*)d_in[22];

  // ---- workspace tiering (deterministic in ws_size) ----
  const size_t MB = 1024 * 1024;
  int gb; bool s4;                           // batches per attention group; split-K=4 path
  if      (ws_size >= 236 * MB) { gb = 4; s4 = true;  }
  else if (ws_size >= 169 * MB) { gb = 2; s4 = true;  }
  else if (ws_size >= 152 * MB) { gb = 1; s4 = true;  }
  else                          { gb = 1; s4 = false; }   // == round-4 layout (~110 MB)

  const size_t qkBytes = (size_t)gb * 1024 * 8192 * 2;
  const size_t scB0    = (size_t)gb * 8 * 1024 * 1024 * 2;
  const size_t scBytes = s4 ? (scB0 > 33554432 ? scB0 : 33554432) : 16777216;
  const size_t vtB0    = (size_t)gb * 8 * 512 * 1024 * 2;
  const size_t vtBytes = s4 ? (vtB0 > 33554432 ? vtB0 : 33554432) : 8388608;

  char* wsp = (char*)d_ws;
  auto alloc = [&](size_t bytes) { char* p = wsp; wsp += (bytes + 255) & ~(size_t)255; return p; };

  bfu*   qkvwT = (bfu*)  alloc(12288L * 512 * 2);
  bfu*   woT   = (bfu*)  alloc(512L * 4096 * 2);
  bfu*   w1T   = (bfu*)  alloc(2048L * 512 * 2);
  bfu*   w2T   = (bfu*)  alloc(512L * 2048 * 2);
  bfu*   woutT = (bfu*)  alloc(512L * 512 * 2);
  float* qkb   = (float*)alloc(8192L * 4);
  float* h     = (float*)alloc(4096L * 512 * 4);        // fp32 residual stream
  bfu*   hb    = (bfu*)  alloc(4096L * 512 * 2);        // bf16 copy (GEMM A operand)
  bfu*   attn  = (bfu*)  alloc(4096L * 4096 * 2);       // attention out, all tokens
  bfu*   qkS   = (bfu*)  alloc(qkBytes);                // q|k group; (!s4) FFN2/final partials
  bfu*   scS   = (bfu*)  alloc(scBytes);                // scores; Wo partials; FFN hidden
  bfu*   vTS   = (bfu*)  alloc(vtBytes);                // v^T group; (s4) FFN2/final partials

  float* pWo = (float*)scS;
  float* pF  = s4 ? (float*)vTS : (float*)qkS;
  const int nspl = s4 ? 4 : 2;

  embed_ln<<<4096, 256, 0, stream>>>(x, tok, pos, lnig, lnib, h, hb);
  transpose_cvt<<<dim3(8, 8), 256, 0, stream>>>(Wout, woutT, 512, 512);

  const float invsq = 0.044194173824159216f;  // 1/sqrt(512)
  const long  PSTR  = 4096L * 512;            // split-K partial stride (floats)

  for (int l = 0; l < 6; l++) {
    prep_layer<<<2592, 256, 0, stream>>>(
        Wq + (long)l*512*4096, Wk + (long)l*512*4096, Wv + (long)l*512*4096,
        Wo + (long)l*4096*512, W1 + (long)l*512*2048, W2 + (long)l*2048*512,
        bq + (long)l*4096, bk + (long)l*4096,
        qkvwT, woT, w1T, w2T, qkb);

    for (int g0 = 0; g0 < 4; g0 += gb) {
      const bfu* hbG = hb + (long)g0 * 1024 * 512;

      // q|k: [gb*1024,512] x [8192,512]^T -> qkS (+col bias)
      gemm_bt<128,128,2,2,4,4,true,false,false,1,false>
          <<<dim3(64, gb*8, 1), 256, 0, stream>>>(
          hbG, 512, 0, 0, qkvwT, 512, 0, 0, qkS, 8192, 0, 0,
          qkb, 512, 1, 1.0f, 8);

      // vT[b][h][d][s] = Wv^T @ h_b^T (+row bias): z = batch
      gemm_bt<128,128,2,2,4,4,true,false,false,2,false>
          <<<dim3(8, 32, gb), 256, 0, stream>>>(
          qkvwT + 8192L*512, 512, 0, 0,
          hbG, 512, 0, 1024L*512,
          vTS, 1024, 0, 4096L*1024,
          bv + (long)l*4096, 512, gb, 1.0f, 8);

      // scores = (q k^T)/sqrt(dh), causal (upper tiles skipped): z = b*8+h
      gemm_bt<128,128,2,2,4,4,true,false,true,0,false>
          <<<dim3(8, 8, gb*8), 256, 0, stream>>>(
          qkS,        8192, 1024L*8192, 512,
          qkS + 4096, 8192, 1024L*8192, 512,
          scS, 1024, 8L*1024*1024, 1024L*1024,
          nullptr, 512, 8, invsq, 8);

      softmax_causal<<<gb*8192, 256, 0, stream>>>(scS);

      // attn = P @ v, triangular K: z = b*8+h
      gemm_bt<128,64,2,2,4,2,true,false,false,0,true>
          <<<dim3(8, 8, gb*8), 256, 0, stream>>>(
          scS, 1024, 8L*1024*1024, 1024L*1024,
          vTS, 1024, 8L*512*1024,  512L*1024,
          attn + (long)g0*1024*4096, 4096, 1024L*4096, 512,
          nullptr, 1024, 8, 1.0f, 8);
    }

    // Wo projection -> fp32 partials
    if (s4) {
      gemm_bt<128,128,2,2,4,4,false,false,false,0,false>
          <<<dim3(4, 32, 4), 256, 0, stream>>>(
          attn, 4096, 0, 1024, woT, 4096, 0, 1024,
          pWo, 512, 0, PSTR, nullptr, 1024, 4, 1.0f, 4);
    } else {
      gemm_bt<128,64,2,2,4,2,false,false,false,0,false>
          <<<dim3(8, 32, 2), 256, 0, stream>>>(
          attn, 4096, 0, 2048, woT, 4096, 0, 2048,
          pWo, 512, 0, PSTR, nullptr, 2048, 1, 1.0f, 8);
    }
    add_ln_redN<<<4096, 256, 0, stream>>>(pWo, PSTR, nspl, bo + (long)l*512,
                                          h, hb, ln1g + (long)l*512, ln1b + (long)l*512);

    // FFN1 (+ReLU) -> bf16 hidden in scS [4096,2048]
    gemm_bt<128,128,2,2,4,4,true,true,false,1,false>
        <<<dim3(16, 32, 1), 256, 0, stream>>>(
        hb, 512, 0, 0, w1T, 512, 0, 0, scS, 2048, 0, 0,
        b1 + (long)l*2048, 512, 1, 1.0f, 16);

    // FFN2 -> fp32 partials
    if (s4) {
      gemm_bt<128,128,2,2,4,4,false,false,false,0,false>
          <<<dim3(4, 32, 4), 256, 0, stream>>>(
          scS, 2048, 0, 512, w2T, 2048, 0, 512,
          pF, 512, 0, PSTR, nullptr, 512, 4, 1.0f, 4);
    } else {
      gemm_bt<128,64,2,2,4,2,false,false,false,0,false>
          <<<dim3(8, 32, 2), 256, 0, stream>>>(
          scS, 2048, 0, 1024, w2T, 2048, 0, 1024,
          pF, 512, 0, PSTR, nullptr, 1024, 1, 1.0f, 8);
    }
    add_ln_redN<<<4096, 256, 0, stream>>>(pF, PSTR, nspl, b2 + (long)l*512,
                                          h, hb, ln2g + (long)l*512, ln2b + (long)l*512);
  }

  // final projection (K=128 per split: multiple of 64 ✓)
  if (s4) {
    gemm_bt<128,128,2,2,4,4,false,false,false,0,false>
        <<<dim3(4, 32, 4), 256, 0, stream>>>(
        hb, 512, 0, 128, woutT, 512, 0, 128,
        pF, 512, 0, PSTR, nullptr, 128, 4, 1.0f, 4);
  } else {
    gemm_bt<128,64,2,2,4,2,false,false,false,0,false>
        <<<dim3(8, 32, 2), 256, 0, stream>>>(
        hb, 512, 0, 256, woutT, 512, 0, 256,
        pF, 512, 0, PSTR, nullptr, 256, 1, 1.0f, 8);
  }
  out_redN<<<4096, 256, 0, stream>>>(pF, PSTR, nspl, bout, (float*)d_out);
}